// Round 1
// baseline (376.290 us; speedup 1.0000x reference)
//
#include <hip/hip_runtime.h>
#include <hip/hip_bf16.h>
#include <math.h>

// Problem constants: N=100000, E=600000, D=128, H=4, F=32, L=3

__device__ __forceinline__ float leaky02(float x) {
    return x >= 0.f ? x : 0.2f * x;
}
__device__ __forceinline__ float leaky01(float x) {
    return x >= 0.f ? x : 0.01f * x;
}

// bf16 helpers (round-to-nearest-even)
__device__ __forceinline__ unsigned short f2bf(float f) {
    unsigned u = __float_as_uint(f);
    unsigned r = u + 0x7FFFu + ((u >> 16) & 1u);
    return (unsigned short)(r >> 16);
}
__device__ __forceinline__ float bf2f(unsigned short s) {
    return __uint_as_float(((unsigned)s) << 16);
}

typedef __attribute__((ext_vector_type(8))) short bf16x8;
typedef __attribute__((ext_vector_type(8))) unsigned short u16x8;
typedef __attribute__((ext_vector_type(4))) float f32x4;

// ---------------------------------------------------------------------------
// Fused init: deg[i]=1 + W split into bf16 hi/lo, PACKED IN FRAGMENT ORDER:
// packed index p = ((kk*8 + c)*64 + lane)*8 + j  <-  W[(c*16+(lane&15))*128
// + kk*32 + (lane>>4)*8 + j]. Wave B-fragment load = base + lane*16B.
__global__ __launch_bounds__(256) void init_split_kernel(
    int* __restrict__ deg, int N, const float* __restrict__ W,
    short* __restrict__ Wh, short* __restrict__ Wl, int n)
{
    int i = blockIdx.x * 256 + threadIdx.x;
    if (i < N) deg[i] = 1;
    if (i < n) {
        int l    = i >> 14;          // layer (0,1)
        int p    = i & 16383;
        int j    = p & 7;
        int lane = (p >> 3) & 63;
        int c    = (p >> 9) & 7;
        int kk   = p >> 12;
        int mr   = lane & 15;
        int quad = lane >> 4;
        int row  = c * 16 + mr;
        int d    = kk * 32 + quad * 8 + j;
        float f = W[(size_t)l * 16384 + row * 128 + d];
        unsigned short hi = f2bf(f);
        Wh[i] = (short)hi;
        Wl[i] = (short)f2bf(f - bf2f(hi));
    }
}

// Mext[r][d] per layer: r 0..3 = Wt@Al head r, r 4..7 = Wt@Ar, r 8..15 = 0.
__global__ __launch_bounds__(128) void mlr_prep_kernel(
    const float* __restrict__ fc_W, const float* __restrict__ attn_l,
    const float* __restrict__ attn_r, short* __restrict__ Mh,
    short* __restrict__ Ml)
{
    int l = blockIdx.x;                       // 0,1 -> layers 1,2
    const float* W  = fc_W + (size_t)(l + 1) * 16384;
    const float* al = attn_l + (l + 1) * 128;
    const float* ar = attn_r + (l + 1) * 128;
    short* mh = Mh + (size_t)l * 16 * 128;
    short* ml = Ml + (size_t)l * 16 * 128;
    int d = threadIdx.x;
#pragma unroll
    for (int r = 0; r < 8; ++r) {
        int hh = r & 3;
        const float* av = (r < 4) ? al : ar;
        float s = 0.f;
        for (int f = 0; f < 32; ++f)
            s += W[(size_t)(hh * 32 + f) * 128 + d] * av[hh * 32 + f];
        unsigned short hi = f2bf(s);
        mh[r * 128 + d] = (short)hi;
        ml[r * 128 + d] = (short)f2bf(s - bf2f(hi));
    }
#pragma unroll
    for (int r = 8; r < 16; ++r) { mh[r * 128 + d] = 0; ml[r * 128 + d] = 0; }
}

// slot[i] = old count (>=1 because self loop holds slot 0)
__global__ __launch_bounds__(256) void deg_count_slot_kernel(
    const int* __restrict__ dst, int* __restrict__ deg,
    int* __restrict__ slot, int E)
{
    int i = blockIdx.x * 256 + threadIdx.x;
    if (i < E) slot[i] = atomicAdd(&deg[dst[i]], 1);
}

#define SCAN_TILE 1024

__global__ __launch_bounds__(256) void scanA_kernel(
    const int* __restrict__ deg, int* __restrict__ bsum, int N)
{
    __shared__ int ws[4];
    int b = blockIdx.x, t = threadIdx.x;
    int base = b * SCAN_TILE + t * 4;
    int s = 0;
#pragma unroll
    for (int k = 0; k < 4; ++k) {
        int i = base + k;
        if (i < N) s += deg[i];
    }
#pragma unroll
    for (int m = 32; m >= 1; m >>= 1) s += __shfl_xor(s, m, 64);
    if ((t & 63) == 0) ws[t >> 6] = s;
    __syncthreads();
    if (t == 0) bsum[b] = ws[0] + ws[1] + ws[2] + ws[3];
}

__global__ __launch_bounds__(1024) void scanB_kernel(
    int* __restrict__ bsum, int* __restrict__ bpre, int* __restrict__ rowp,
    int NB, int N)
{
    __shared__ int sh[1024];
    int t = threadIdx.x;
    int v = (t < NB) ? bsum[t] : 0;
    sh[t] = v;
    __syncthreads();
    for (int off = 1; off < 1024; off <<= 1) {
        int u = (t >= off) ? sh[t - off] : 0;
        __syncthreads();
        sh[t] += u;
        __syncthreads();
    }
    if (t < NB) bpre[t] = sh[t] - v;          // exclusive prefix
    if (t == 1023) rowp[N] = sh[1023];        // total
}

// scanC also writes the self-loop entry: col[rowp[i]] = i (slot 0).
__global__ __launch_bounds__(256) void scanC_kernel(
    const int* __restrict__ deg, const int* __restrict__ bpre,
    int* __restrict__ rowp, int* __restrict__ col, int N)
{
    __shared__ int sh[256];
    int b = blockIdx.x, t = threadIdx.x;
    int base = b * SCAN_TILE + t * 4;
    int v[4];
#pragma unroll
    for (int k = 0; k < 4; ++k) {
        int i = base + k;
        v[k] = (i < N) ? deg[i] : 0;
    }
    int tsum = v[0] + v[1] + v[2] + v[3];
    sh[t] = tsum;
    __syncthreads();
    for (int off = 1; off < 256; off <<= 1) {
        int u = (t >= off) ? sh[t - off] : 0;
        __syncthreads();
        sh[t] += u;
        __syncthreads();
    }
    int pre = bpre[b] + sh[t] - tsum;
#pragma unroll
    for (int k = 0; k < 4; ++k) {
        int i = base + k;
        if (i < N) {
            rowp[i] = pre;
            col[pre] = i;   // self loop at slot 0
        }
        pre += v[k];
    }
}

// atomic-free scatter: position fully determined by rowp + recorded slot
__global__ __launch_bounds__(256) void scatter2_kernel(
    const int* __restrict__ src, const int* __restrict__ dst,
    const int* __restrict__ slot, const int* __restrict__ rowp,
    int* __restrict__ col, int E)
{
    int i = blockIdx.x * 256 + threadIdx.x;
    if (i < E) col[rowp[dst[i]] + slot[i]] = src[i];
}

// ---------------------------------------------------------------------------
// Layer-0 rank-1 precompute
__global__ __launch_bounds__(128) void rank1_prep_kernel(
    const float* __restrict__ lW, const float* __restrict__ lb,
    const float* __restrict__ W0, const float* __restrict__ al,
    const float* __restrict__ ar, float* __restrict__ c1,
    float* __restrict__ c2, float* __restrict__ prm)
{
    int j = threadIdx.x;
    float s1 = 0.f, s2 = 0.f;
    for (int d = 0; d < 128; ++d) {
        float wv = W0[j * 128 + d];
        s1 += lW[d] * wv;
        s2 += lb[d] * wv;
    }
    c1[j] = s1; c2[j] = s2;
    __shared__ float sh1[128], sh2[128], sh3[128], sh4[128];
    sh1[j] = s1 * al[j]; sh2[j] = s2 * al[j];
    sh3[j] = s1 * ar[j]; sh4[j] = s2 * ar[j];
    __syncthreads();
    if (j < 4) {
        float p = 0.f, q = 0.f, r = 0.f, s = 0.f;
        for (int f = 0; f < 32; ++f) {
            p += sh1[j * 32 + f]; q += sh2[j * 32 + f];
            r += sh3[j * 32 + f]; s += sh4[j * 32 + f];
        }
        prm[j] = p; prm[4 + j] = q; prm[8 + j] = r; prm[12 + j] = s;
    }
}

// h0 (bf16) = w[n]*c1[j] + c2[j]; el0/er0 from rank-1 params.
__global__ __launch_bounds__(256) void rank1_apply_kernel(
    const float* __restrict__ w, const float* __restrict__ c1,
    const float* __restrict__ c2, const float* __restrict__ prm,
    unsigned short* __restrict__ hb, float* __restrict__ el,
    float* __restrict__ er, int N)
{
    int i = blockIdx.x * 256 + threadIdx.x;
    int n = i >> 5, k = i & 31;
    if (n >= N) return;
    float wn = w[n];
    float4 a = *reinterpret_cast<const float4*>(&c1[k * 4]);
    float4 b = *reinterpret_cast<const float4*>(&c2[k * 4]);
    ushort4 o;
    o.x = f2bf(wn * a.x + b.x);
    o.y = f2bf(wn * a.y + b.y);
    o.z = f2bf(wn * a.z + b.z);
    o.w = f2bf(wn * a.w + b.w);
    *reinterpret_cast<ushort4*>(&hb[(size_t)n * 128 + k * 4]) = o;
    if (k == 0) {
        float4 pl = *reinterpret_cast<const float4*>(&prm[0]);
        float4 ql = *reinterpret_cast<const float4*>(&prm[4]);
        float4 pr = *reinterpret_cast<const float4*>(&prm[8]);
        float4 qr = *reinterpret_cast<const float4*>(&prm[12]);
        float4 e1 = make_float4(wn * pl.x + ql.x, wn * pl.y + ql.y,
                                wn * pl.z + ql.z, wn * pl.w + ql.w);
        float4 e2 = make_float4(wn * pr.x + qr.x, wn * pr.y + qr.y,
                                wn * pr.z + qr.z, wn * pr.w + qr.w);
        *reinterpret_cast<float4*>(&el[(size_t)n * 4]) = e1;
        *reinterpret_cast<float4*>(&er[(size_t)n * 4]) = e2;
    }
}

// ---------------------------------------------------------------------------
// MFMA bf16 GEMM (layers 1,2) + fused el/er tile — 32 rows/wave,
// FRAGMENT-PACKED W (every bh/bl load = base + lane*16B = one coalesced
// 1 KB transaction — the R21 winner). x stays row-major (R22's packed-x
// was neutral/negative: it traded gemm load coalescing for agg store
// scatter).
__global__ __launch_bounds__(256) void gemm_mfma_kernel(
    const unsigned short* __restrict__ xb, const short* __restrict__ Wh,
    const short* __restrict__ Wl, const short* __restrict__ Mh,
    const short* __restrict__ Ml, unsigned short* __restrict__ hb,
    float* __restrict__ el, float* __restrict__ er, int N)
{
    const int lane = threadIdx.x & 63;
    const int wv   = threadIdx.x >> 6;
    const int m0   = blockIdx.x * 128 + wv * 32;  // 32 rows per wave
    const int mr   = lane & 15;
    const int quad = lane >> 4;

    int r0 = m0 + mr;      if (r0 > N - 1) r0 = N - 1;   // clamped load rows
    int r1 = m0 + 16 + mr; if (r1 > N - 1) r1 = N - 1;
    const unsigned short* xp0 = xb + (size_t)r0 * 128 + quad * 8;
    const unsigned short* xp1 = xb + (size_t)r1 * 128 + quad * 8;

    f32x4 acc0[8], acc1[8], acce0, acce1;
#pragma unroll
    for (int c = 0; c < 8; ++c) {
        acc0[c] = (f32x4){0.f, 0.f, 0.f, 0.f};
        acc1[c] = (f32x4){0.f, 0.f, 0.f, 0.f};
    }
    acce0 = (f32x4){0.f, 0.f, 0.f, 0.f};
    acce1 = (f32x4){0.f, 0.f, 0.f, 0.f};

#pragma unroll
    for (int kk = 0; kk < 4; ++kk) {
        bf16x8 a0 = *reinterpret_cast<const bf16x8*>(xp0 + kk * 32);
        bf16x8 a1 = *reinterpret_cast<const bf16x8*>(xp1 + kk * 32);

        const int kb = kk * 32 + quad * 8;
        // packed W: fragment (kk,c) lives at ((kk*8+c)*64 + lane)*8
        bf16x8 bh[8], bl[8];
#pragma unroll
        for (int c = 0; c < 8; ++c) {
            const size_t wo = (size_t)((kk * 8 + c) * 64 + lane) * 8;
            bh[c] = *reinterpret_cast<const bf16x8*>(Wh + wo);
            bl[c] = *reinterpret_cast<const bf16x8*>(Wl + wo);
        }
        bf16x8 eh = *reinterpret_cast<const bf16x8*>(Mh + (size_t)mr * 128 + kb);
        bf16x8 eo = *reinterpret_cast<const bf16x8*>(Ml + (size_t)mr * 128 + kb);
#pragma unroll
        for (int c = 0; c < 8; ++c) {
            acc0[c] = __builtin_amdgcn_mfma_f32_16x16x32_bf16(a0, bh[c], acc0[c], 0, 0, 0);
            acc0[c] = __builtin_amdgcn_mfma_f32_16x16x32_bf16(a0, bl[c], acc0[c], 0, 0, 0);
            acc1[c] = __builtin_amdgcn_mfma_f32_16x16x32_bf16(a1, bh[c], acc1[c], 0, 0, 0);
            acc1[c] = __builtin_amdgcn_mfma_f32_16x16x32_bf16(a1, bl[c], acc1[c], 0, 0, 0);
        }
        acce0 = __builtin_amdgcn_mfma_f32_16x16x32_bf16(a0, eh, acce0, 0, 0, 0);
        acce0 = __builtin_amdgcn_mfma_f32_16x16x32_bf16(a0, eo, acce0, 0, 0, 0);
        acce1 = __builtin_amdgcn_mfma_f32_16x16x32_bf16(a1, eh, acce1, 0, 0, 0);
        acce1 = __builtin_amdgcn_mfma_f32_16x16x32_bf16(a1, eo, acce1, 0, 0, 0);
    }

#pragma unroll
    for (int i = 0; i < 4; ++i) {
        int rowA = m0 + quad * 4 + i;
        if (rowA < N) {
            unsigned short* hp = hb + (size_t)rowA * 128 + mr;
#pragma unroll
            for (int c = 0; c < 8; ++c) hp[c * 16] = f2bf(acc0[c][i]);
            if (mr < 4)       el[(size_t)rowA * 4 + mr]       = acce0[i];
            else if (mr < 8)  er[(size_t)rowA * 4 + (mr - 4)] = acce0[i];
        }
        int rowB = m0 + 16 + quad * 4 + i;
        if (rowB < N) {
            unsigned short* hp = hb + (size_t)rowB * 128 + mr;
#pragma unroll
            for (int c = 0; c < 8; ++c) hp[c * 16] = f2bf(acc1[c][i]);
            if (mr < 4)       el[(size_t)rowB * 4 + mr]       = acce1[i];
            else if (mr < 8)  er[(size_t)rowB * 4 + (mr - 4)] = acce1[i];
        }
    }
}

// ---------------------------------------------------------------------------
// EDGE-PARALLEL fused online-softmax aggregation + epilogue.
// One wave = one vertex: 4 edge-slots x 16 feature-lanes. Each iteration
// gathers 4 edges' h-rows in parallel (4x the MLP of the old edge-serial
// loop) and the next chunk's col is prefetched one iteration ahead, so the
// col->gather dependent chain is ~2 iterations deep instead of ~10.
// Per-slot online-softmax states merge with a 2-step shfl_xor butterfly
// (associative online-softmax combine). Inactive slots use a finite -1e30
// sentinel (NOT -inf: -inf - -inf = NaN) with p explicitly zeroed, and
// gathers clamp to col[r1-1] so masked lanes never touch garbage.
#define NEG_SENT -1e30f
__global__ __launch_bounds__(256) void agg_fused_kernel(
    const unsigned short* __restrict__ hb, const float* __restrict__ el,
    const float* __restrict__ er, const int* __restrict__ rowp,
    const int* __restrict__ col, const float* __restrict__ bias,
    unsigned short* __restrict__ xout, const float* __restrict__ pW,
    const float* __restrict__ pb, float* __restrict__ logits,
    int N, int last)
{
    const int lane = threadIdx.x & 63;
    const int es   = lane >> 4;        // edge slot 0..3
    const int l16  = lane & 15;
    const int v    = blockIdx.x * 4 + (threadIdx.x >> 6);   // 1 vertex / wave
    if (v >= N) return;

    const int r0 = rowp[v], r1 = rowp[v + 1];   // r1 > r0 (self loop)
    const int head = l16 >> 2;       // head for this lane's 8 features
    const int f0   = l16 * 8;        // feature base 0..120
    const float erq = er[(size_t)v * 4 + head];

    float m = NEG_SENT, s = 0.f;
    float acc[8];
#pragma unroll
    for (int k = 0; k < 8; ++k) acc[k] = 0.f;

    // prefetched col for the first chunk (clamped: always a valid edge)
    int j0  = r0 + es;
    int u   = col[j0 < r1 ? j0 : r1 - 1];

    for (int base = r0; base < r1; base += 4) {
        const int  jj  = base + es;
        const bool act = jj < r1;
        // prefetch next chunk's col (clamped) before the dependent gathers
        int jn = jj + 4;
        int u_next = col[jn < r1 ? jn : r1 - 1];

        float elv = el[(size_t)u * 4 + head];
        u16x8 hv  = *reinterpret_cast<const u16x8*>(&hb[(size_t)u * 128 + f0]);

        float e  = act ? leaky02(elv + erq) : NEG_SENT;
        float nm = fmaxf(m, e);
        float sc = __expf(m - nm);           // 1 when both sentinel (harmless)
        float p  = act ? __expf(e - nm) : 0.f;
        s = s * sc + p;
#pragma unroll
        for (int k = 0; k < 8; ++k) acc[k] = acc[k] * sc + p * bf2f(hv[k]);
        m = nm;
        u = u_next;
    }

    // merge the 4 edge-slot groups (lanes differing in bits 4,5)
#pragma unroll
    for (int d = 16; d <= 32; d <<= 1) {
        float m2 = __shfl_xor(m, d, 64);
        float s2 = __shfl_xor(s, d, 64);
        float nm = fmaxf(m, m2);
        float a  = __expf(m - nm);           // exp(0)=1 when both sentinel
        float b  = __expf(m2 - nm);
        s = s * a + s2 * b;
#pragma unroll
        for (int k = 0; k < 8; ++k) {
            float a2 = __shfl_xor(acc[k], d, 64);
            acc[k] = acc[k] * a + a2 * b;
        }
        m = nm;
    }
    const float is = 1.f / s;

    float4 b0 = *reinterpret_cast<const float4*>(&bias[f0]);
    float4 b1 = *reinterpret_cast<const float4*>(&bias[f0 + 4]);
    const float bb[8] = {b0.x, b0.y, b0.z, b0.w, b1.x, b1.y, b1.z, b1.w};

    if (last) {
        float4 p0 = *reinterpret_cast<const float4*>(&pW[f0]);
        float4 p1 = *reinterpret_cast<const float4*>(&pW[f0 + 4]);
        const float pp[8] = {p0.x, p0.y, p0.z, p0.w, p1.x, p1.y, p1.z, p1.w};
        float part = 0.f;
#pragma unroll
        for (int k = 0; k < 8; ++k) part += (acc[k] * is + bb[k]) * pp[k];
#pragma unroll
        for (int d = 1; d <= 8; d <<= 1) part += __shfl_xor(part, d, 64);
        if (lane == 0) logits[v] = part + pb[0];
    } else if (es == 0) {
        u16x8 o;
#pragma unroll
        for (int k = 0; k < 8; ++k) o[k] = f2bf(leaky01(acc[k] * is + bb[k]));
        *reinterpret_cast<u16x8*>(&xout[(size_t)v * 128 + f0]) = o;
    }
}

// ---------------------------------------------------------------------------
extern "C" void kernel_launch(void* const* d_in, const int* in_sizes, int n_in,
                              void* d_out, int out_size, void* d_ws, size_t ws_size,
                              hipStream_t stream)
{
    const float* weights = (const float*)d_in[0];
    const float* lin_W   = (const float*)d_in[1];
    const float* lin_b   = (const float*)d_in[2];
    const float* fc_W    = (const float*)d_in[3];
    const float* attn_l  = (const float*)d_in[4];
    const float* attn_r  = (const float*)d_in[5];
    const float* conv_b  = (const float*)d_in[6];
    const float* pred_W  = (const float*)d_in[7];
    const float* pred_b  = (const float*)d_in[8];
    const int*   src     = (const int*)d_in[9];
    const int*   dst     = (const int*)d_in[10];

    const int N = in_sizes[0];
    const int E = in_sizes[9];
    const int NB = (N + SCAN_TILE - 1) / SCAN_TILE;

    // workspace layout (16B-aligned sections)
    unsigned short* xb = (unsigned short*)d_ws;                    // N*128 bf16 (pre-activated)
    unsigned short* hb = xb + (size_t)N * 128;                     // N*128 bf16
    float* el  = (float*)(hb + (size_t)N * 128);                   // N*4
    float* er  = el + (size_t)N * 4;                               // N*4
    float* c1  = er + (size_t)N * 4;                               // 128
    float* c2  = c1 + 128;                                         // 128
    float* prm = c2 + 128;                                         // 16
    short* Whs = (short*)(prm + 16);                               // 2*16384 bf16 (packed)
    short* Wls = Whs + 2 * 16384;                                  // 2*16384 bf16 (packed)
    short* Mhs = Wls + 2 * 16384;                                  // 2*2048 bf16 (Mext hi)
    short* Mls = Mhs + 2 * 2048;                                   // 2*2048 bf16 (Mext lo)
    int*   deg  = (int*)(Mls + 2 * 2048);                          // N
    int*   rowp = deg + N;                                         // N+1
    int*   slot = rowp + (N + 1);                                  // E
    int*   col  = slot + E;                                        // E+N
    int*   bsum = col + (E + N);                                   // NB
    int*   bpre = bsum + NB;                                       // NB

    // CSR build + packed W split (fresh every call: ws is re-poisoned)
    init_split_kernel<<<(N + 255) / 256, 256, 0, stream>>>(
        deg, N, fc_W + 16384, Whs, Wls, 2 * 16384);
    mlr_prep_kernel<<<2, 128, 0, stream>>>(fc_W, attn_l, attn_r, Mhs, Mls);
    deg_count_slot_kernel<<<(E + 255) / 256, 256, 0, stream>>>(dst, deg, slot, E);
    scanA_kernel<<<NB, 256, 0, stream>>>(deg, bsum, N);
    scanB_kernel<<<1, 1024, 0, stream>>>(bsum, bpre, rowp, NB, N);
    scanC_kernel<<<NB, 256, 0, stream>>>(deg, bpre, rowp, col, N);
    scatter2_kernel<<<(E + 255) / 256, 256, 0, stream>>>(src, dst, slot, rowp, col, E);

    // Layer 0 via rank-1 identity
    rank1_prep_kernel<<<1, 128, 0, stream>>>(lin_W, lin_b, fc_W, attn_l, attn_r,
                                             c1, c2, prm);
    rank1_apply_kernel<<<((size_t)N * 32 + 255) / 256, 256, 0, stream>>>(
        weights, c1, c2, prm, hb, el, er, N);
    agg_fused_kernel<<<(N + 3) / 4, 256, 0, stream>>>(
        hb, el, er, rowp, col, conv_b, xb, pred_W, pred_b, (float*)d_out, N, 0);

    // Layers 1, 2 (MFMA bf16 gemm, 32 rows/wave, packed W, fused el/er)
    for (int l = 1; l < 3; ++l) {
        gemm_mfma_kernel<<<(N + 127) / 128, 256, 0, stream>>>(
            xb, Whs + (size_t)(l - 1) * 16384, Wls + (size_t)(l - 1) * 16384,
            Mhs + (size_t)(l - 1) * 2048, Mls + (size_t)(l - 1) * 2048,
            hb, el, er, N);
        agg_fused_kernel<<<(N + 3) / 4, 256, 0, stream>>>(
            hb, el, er, rowp, col, conv_b + l * 128, xb, pred_W, pred_b,
            (float*)d_out, N, l == 2 ? 1 : 0);
    }
}

// Round 2
// 358.468 us; speedup vs baseline: 1.0497x; 1.0497x over previous
//
#include <hip/hip_runtime.h>
#include <hip/hip_bf16.h>
#include <math.h>

// Problem constants: N=100000, E=600000, D=128, H=4, F=32, L=3

__device__ __forceinline__ float leaky02(float x) {
    return x >= 0.f ? x : 0.2f * x;
}
__device__ __forceinline__ float leaky01(float x) {
    return x >= 0.f ? x : 0.01f * x;
}

// bf16 helpers (round-to-nearest-even)
__device__ __forceinline__ unsigned short f2bf(float f) {
    unsigned u = __float_as_uint(f);
    unsigned r = u + 0x7FFFu + ((u >> 16) & 1u);
    return (unsigned short)(r >> 16);
}
__device__ __forceinline__ float bf2f(unsigned short s) {
    return __uint_as_float(((unsigned)s) << 16);
}

typedef __attribute__((ext_vector_type(8))) short bf16x8;
typedef __attribute__((ext_vector_type(8))) unsigned short u16x8;
typedef __attribute__((ext_vector_type(4))) float f32x4;

// ---------------------------------------------------------------------------
// Fused init: deg[i]=1 + W split into bf16 hi/lo, PACKED IN FRAGMENT ORDER:
// packed index p = ((kk*8 + c)*64 + lane)*8 + j  <-  W[(c*16+(lane&15))*128
// + kk*32 + (lane>>4)*8 + j]. Wave B-fragment load = base + lane*16B.
__global__ __launch_bounds__(256) void init_split_kernel(
    int* __restrict__ deg, int N, const float* __restrict__ W,
    short* __restrict__ Wh, short* __restrict__ Wl, int n)
{
    int i = blockIdx.x * 256 + threadIdx.x;
    if (i < N) deg[i] = 1;
    if (i < n) {
        int l    = i >> 14;          // layer (0,1)
        int p    = i & 16383;
        int j    = p & 7;
        int lane = (p >> 3) & 63;
        int c    = (p >> 9) & 7;
        int kk   = p >> 12;
        int mr   = lane & 15;
        int quad = lane >> 4;
        int row  = c * 16 + mr;
        int d    = kk * 32 + quad * 8 + j;
        float f = W[(size_t)l * 16384 + row * 128 + d];
        unsigned short hi = f2bf(f);
        Wh[i] = (short)hi;
        Wl[i] = (short)f2bf(f - bf2f(hi));
    }
}

// Mext[r][d] per layer: r 0..3 = Wt@Al head r, r 4..7 = Wt@Ar, r 8..15 = 0.
__global__ __launch_bounds__(128) void mlr_prep_kernel(
    const float* __restrict__ fc_W, const float* __restrict__ attn_l,
    const float* __restrict__ attn_r, short* __restrict__ Mh,
    short* __restrict__ Ml)
{
    int l = blockIdx.x;                       // 0,1 -> layers 1,2
    const float* W  = fc_W + (size_t)(l + 1) * 16384;
    const float* al = attn_l + (l + 1) * 128;
    const float* ar = attn_r + (l + 1) * 128;
    short* mh = Mh + (size_t)l * 16 * 128;
    short* ml = Ml + (size_t)l * 16 * 128;
    int d = threadIdx.x;
#pragma unroll
    for (int r = 0; r < 8; ++r) {
        int hh = r & 3;
        const float* av = (r < 4) ? al : ar;
        float s = 0.f;
        for (int f = 0; f < 32; ++f)
            s += W[(size_t)(hh * 32 + f) * 128 + d] * av[hh * 32 + f];
        unsigned short hi = f2bf(s);
        mh[r * 128 + d] = (short)hi;
        ml[r * 128 + d] = (short)f2bf(s - bf2f(hi));
    }
#pragma unroll
    for (int r = 8; r < 16; ++r) { mh[r * 128 + d] = 0; ml[r * 128 + d] = 0; }
}

// slot[i] = old count (>=1 because self loop holds slot 0)
__global__ __launch_bounds__(256) void deg_count_slot_kernel(
    const int* __restrict__ dst, int* __restrict__ deg,
    int* __restrict__ slot, int E)
{
    int i = blockIdx.x * 256 + threadIdx.x;
    if (i < E) slot[i] = atomicAdd(&deg[dst[i]], 1);
}

#define SCAN_TILE 1024

__global__ __launch_bounds__(256) void scanA_kernel(
    const int* __restrict__ deg, int* __restrict__ bsum, int N)
{
    __shared__ int ws[4];
    int b = blockIdx.x, t = threadIdx.x;
    int base = b * SCAN_TILE + t * 4;
    int s = 0;
#pragma unroll
    for (int k = 0; k < 4; ++k) {
        int i = base + k;
        if (i < N) s += deg[i];
    }
#pragma unroll
    for (int m = 32; m >= 1; m >>= 1) s += __shfl_xor(s, m, 64);
    if ((t & 63) == 0) ws[t >> 6] = s;
    __syncthreads();
    if (t == 0) bsum[b] = ws[0] + ws[1] + ws[2] + ws[3];
}

__global__ __launch_bounds__(1024) void scanB_kernel(
    int* __restrict__ bsum, int* __restrict__ bpre, int* __restrict__ rowp,
    int NB, int N)
{
    __shared__ int sh[1024];
    int t = threadIdx.x;
    int v = (t < NB) ? bsum[t] : 0;
    sh[t] = v;
    __syncthreads();
    for (int off = 1; off < 1024; off <<= 1) {
        int u = (t >= off) ? sh[t - off] : 0;
        __syncthreads();
        sh[t] += u;
        __syncthreads();
    }
    if (t < NB) bpre[t] = sh[t] - v;          // exclusive prefix
    if (t == 1023) rowp[N] = sh[1023];        // total
}

// scanC also writes the self-loop entry: col[rowp[i]] = i (slot 0).
__global__ __launch_bounds__(256) void scanC_kernel(
    const int* __restrict__ deg, const int* __restrict__ bpre,
    int* __restrict__ rowp, int* __restrict__ col, int N)
{
    __shared__ int sh[256];
    int b = blockIdx.x, t = threadIdx.x;
    int base = b * SCAN_TILE + t * 4;
    int v[4];
#pragma unroll
    for (int k = 0; k < 4; ++k) {
        int i = base + k;
        v[k] = (i < N) ? deg[i] : 0;
    }
    int tsum = v[0] + v[1] + v[2] + v[3];
    sh[t] = tsum;
    __syncthreads();
    for (int off = 1; off < 256; off <<= 1) {
        int u = (t >= off) ? sh[t - off] : 0;
        __syncthreads();
        sh[t] += u;
        __syncthreads();
    }
    int pre = bpre[b] + sh[t] - tsum;
#pragma unroll
    for (int k = 0; k < 4; ++k) {
        int i = base + k;
        if (i < N) {
            rowp[i] = pre;
            col[pre] = i;   // self loop at slot 0
        }
        pre += v[k];
    }
}

// atomic-free scatter: position fully determined by rowp + recorded slot
__global__ __launch_bounds__(256) void scatter2_kernel(
    const int* __restrict__ src, const int* __restrict__ dst,
    const int* __restrict__ slot, const int* __restrict__ rowp,
    int* __restrict__ col, int E)
{
    int i = blockIdx.x * 256 + threadIdx.x;
    if (i < E) col[rowp[dst[i]] + slot[i]] = src[i];
}

// ---------------------------------------------------------------------------
// Layer-0 rank-1 precompute
__global__ __launch_bounds__(128) void rank1_prep_kernel(
    const float* __restrict__ lW, const float* __restrict__ lb,
    const float* __restrict__ W0, const float* __restrict__ al,
    const float* __restrict__ ar, float* __restrict__ c1,
    float* __restrict__ c2, float* __restrict__ prm)
{
    int j = threadIdx.x;
    float s1 = 0.f, s2 = 0.f;
    for (int d = 0; d < 128; ++d) {
        float wv = W0[j * 128 + d];
        s1 += lW[d] * wv;
        s2 += lb[d] * wv;
    }
    c1[j] = s1; c2[j] = s2;
    __shared__ float sh1[128], sh2[128], sh3[128], sh4[128];
    sh1[j] = s1 * al[j]; sh2[j] = s2 * al[j];
    sh3[j] = s1 * ar[j]; sh4[j] = s2 * ar[j];
    __syncthreads();
    if (j < 4) {
        float p = 0.f, q = 0.f, r = 0.f, s = 0.f;
        for (int f = 0; f < 32; ++f) {
            p += sh1[j * 32 + f]; q += sh2[j * 32 + f];
            r += sh3[j * 32 + f]; s += sh4[j * 32 + f];
        }
        prm[j] = p; prm[4 + j] = q; prm[8 + j] = r; prm[12 + j] = s;
    }
}

// h0 (bf16) = w[n]*c1[j] + c2[j]; el0/er0 from rank-1 params.
__global__ __launch_bounds__(256) void rank1_apply_kernel(
    const float* __restrict__ w, const float* __restrict__ c1,
    const float* __restrict__ c2, const float* __restrict__ prm,
    unsigned short* __restrict__ hb, float* __restrict__ el,
    float* __restrict__ er, int N)
{
    int i = blockIdx.x * 256 + threadIdx.x;
    int n = i >> 5, k = i & 31;
    if (n >= N) return;
    float wn = w[n];
    float4 a = *reinterpret_cast<const float4*>(&c1[k * 4]);
    float4 b = *reinterpret_cast<const float4*>(&c2[k * 4]);
    ushort4 o;
    o.x = f2bf(wn * a.x + b.x);
    o.y = f2bf(wn * a.y + b.y);
    o.z = f2bf(wn * a.z + b.z);
    o.w = f2bf(wn * a.w + b.w);
    *reinterpret_cast<ushort4*>(&hb[(size_t)n * 128 + k * 4]) = o;
    if (k == 0) {
        float4 pl = *reinterpret_cast<const float4*>(&prm[0]);
        float4 ql = *reinterpret_cast<const float4*>(&prm[4]);
        float4 pr = *reinterpret_cast<const float4*>(&prm[8]);
        float4 qr = *reinterpret_cast<const float4*>(&prm[12]);
        float4 e1 = make_float4(wn * pl.x + ql.x, wn * pl.y + ql.y,
                                wn * pl.z + ql.z, wn * pl.w + ql.w);
        float4 e2 = make_float4(wn * pr.x + qr.x, wn * pr.y + qr.y,
                                wn * pr.z + qr.z, wn * pr.w + qr.w);
        *reinterpret_cast<float4*>(&el[(size_t)n * 4]) = e1;
        *reinterpret_cast<float4*>(&er[(size_t)n * 4]) = e2;
    }
}

// ---------------------------------------------------------------------------
// MFMA bf16 GEMM (layers 1,2) + fused el/er tile — 32 rows/wave,
// FRAGMENT-PACKED W (every bh/bl load = base + lane*16B = one coalesced
// 1 KB transaction — the R21 winner). x stays row-major.
__global__ __launch_bounds__(256) void gemm_mfma_kernel(
    const unsigned short* __restrict__ xb, const short* __restrict__ Wh,
    const short* __restrict__ Wl, const short* __restrict__ Mh,
    const short* __restrict__ Ml, unsigned short* __restrict__ hb,
    float* __restrict__ el, float* __restrict__ er, int N)
{
    const int lane = threadIdx.x & 63;
    const int wv   = threadIdx.x >> 6;
    const int m0   = blockIdx.x * 128 + wv * 32;  // 32 rows per wave
    const int mr   = lane & 15;
    const int quad = lane >> 4;

    int r0 = m0 + mr;      if (r0 > N - 1) r0 = N - 1;   // clamped load rows
    int r1 = m0 + 16 + mr; if (r1 > N - 1) r1 = N - 1;
    const unsigned short* xp0 = xb + (size_t)r0 * 128 + quad * 8;
    const unsigned short* xp1 = xb + (size_t)r1 * 128 + quad * 8;

    f32x4 acc0[8], acc1[8], acce0, acce1;
#pragma unroll
    for (int c = 0; c < 8; ++c) {
        acc0[c] = (f32x4){0.f, 0.f, 0.f, 0.f};
        acc1[c] = (f32x4){0.f, 0.f, 0.f, 0.f};
    }
    acce0 = (f32x4){0.f, 0.f, 0.f, 0.f};
    acce1 = (f32x4){0.f, 0.f, 0.f, 0.f};

#pragma unroll
    for (int kk = 0; kk < 4; ++kk) {
        bf16x8 a0 = *reinterpret_cast<const bf16x8*>(xp0 + kk * 32);
        bf16x8 a1 = *reinterpret_cast<const bf16x8*>(xp1 + kk * 32);

        const int kb = kk * 32 + quad * 8;
        // packed W: fragment (kk,c) lives at ((kk*8+c)*64 + lane)*8
        bf16x8 bh[8], bl[8];
#pragma unroll
        for (int c = 0; c < 8; ++c) {
            const size_t wo = (size_t)((kk * 8 + c) * 64 + lane) * 8;
            bh[c] = *reinterpret_cast<const bf16x8*>(Wh + wo);
            bl[c] = *reinterpret_cast<const bf16x8*>(Wl + wo);
        }
        bf16x8 eh = *reinterpret_cast<const bf16x8*>(Mh + (size_t)mr * 128 + kb);
        bf16x8 eo = *reinterpret_cast<const bf16x8*>(Ml + (size_t)mr * 128 + kb);
#pragma unroll
        for (int c = 0; c < 8; ++c) {
            acc0[c] = __builtin_amdgcn_mfma_f32_16x16x32_bf16(a0, bh[c], acc0[c], 0, 0, 0);
            acc0[c] = __builtin_amdgcn_mfma_f32_16x16x32_bf16(a0, bl[c], acc0[c], 0, 0, 0);
            acc1[c] = __builtin_amdgcn_mfma_f32_16x16x32_bf16(a1, bh[c], acc1[c], 0, 0, 0);
            acc1[c] = __builtin_amdgcn_mfma_f32_16x16x32_bf16(a1, bl[c], acc1[c], 0, 0, 0);
        }
        acce0 = __builtin_amdgcn_mfma_f32_16x16x32_bf16(a0, eh, acce0, 0, 0, 0);
        acce0 = __builtin_amdgcn_mfma_f32_16x16x32_bf16(a0, eo, acce0, 0, 0, 0);
        acce1 = __builtin_amdgcn_mfma_f32_16x16x32_bf16(a1, eh, acce1, 0, 0, 0);
        acce1 = __builtin_amdgcn_mfma_f32_16x16x32_bf16(a1, eo, acce1, 0, 0, 0);
    }

#pragma unroll
    for (int i = 0; i < 4; ++i) {
        int rowA = m0 + quad * 4 + i;
        if (rowA < N) {
            unsigned short* hp = hb + (size_t)rowA * 128 + mr;
#pragma unroll
            for (int c = 0; c < 8; ++c) hp[c * 16] = f2bf(acc0[c][i]);
            if (mr < 4)       el[(size_t)rowA * 4 + mr]       = acce0[i];
            else if (mr < 8)  er[(size_t)rowA * 4 + (mr - 4)] = acce0[i];
        }
        int rowB = m0 + 16 + quad * 4 + i;
        if (rowB < N) {
            unsigned short* hp = hb + (size_t)rowB * 128 + mr;
#pragma unroll
            for (int c = 0; c < 8; ++c) hp[c * 16] = f2bf(acc1[c][i]);
            if (mr < 4)       el[(size_t)rowB * 4 + mr]       = acce1[i];
            else if (mr < 8)  er[(size_t)rowB * 4 + (mr - 4)] = acce1[i];
        }
    }
}

// ---------------------------------------------------------------------------
// SINGLE-PASS fused aggregation + epilogue — edge-serial 4-vertex/wave
// (R17 structure, proven fastest) with FIXED-REFERENCE softmax:
// the acc/s ratio is invariant to the reference max, so we seed mref with
// the self-loop's e (col[r0]==v by construction -> no gather needed) and
// accumulate p = exp(e - mref) WITHOUT per-edge rescale. This removes the
// fmax/rescale chain (~12 wave-inst/edge, incl. 8 acc-rescale FMAs). A
// rarely-taken guard (d > 50: p up to e^50 ~ 5e21, f32 overflows at e^88)
// rescales if some edge dwarfs the self-loop e, preserving safety.
__global__ __launch_bounds__(256) void agg_fused_kernel(
    const unsigned short* __restrict__ hb, const float* __restrict__ el,
    const float* __restrict__ er, const int* __restrict__ rowp,
    const int* __restrict__ col, const float* __restrict__ bias,
    unsigned short* __restrict__ xout, const float* __restrict__ pW,
    const float* __restrict__ pb, float* __restrict__ logits,
    int N, int last)
{
    const int lane = threadIdx.x & 63;
    const int q    = lane >> 4;
    const int l16  = lane & 15;
    const int v    = blockIdx.x * 16 + (threadIdx.x >> 6) * 4 + q;
    if (v >= N) return;   // reductions below stay within the 16-lane quarter

    const int r0 = rowp[v], r1 = rowp[v + 1];   // r1 > r0 (self loop)
    const int head = l16 >> 2;       // head for this lane's 8 features
    const int f0   = l16 * 8;        // feature base 0..120
    const float erq = er[(size_t)v * 4 + head];
    const float el_self = el[(size_t)v * 4 + head];

    float mref = leaky02(el_self + erq);   // self-loop e: reference max
    float s = 0.f;
    float acc[8];
#pragma unroll
    for (int k = 0; k < 8; ++k) acc[k] = 0.f;

    // prime with edge r0 == self loop (col[r0] == v): no col dependency
    float el_cur = el_self;
    u16x8 hv_cur = *reinterpret_cast<const u16x8*>(&hb[(size_t)v * 128 + f0]);

    for (int j = r0; j < r1; ++j) {
        // issue next edge's loads before this edge's compute
        int jn = (j + 1 < r1) ? (j + 1) : j;
        int   u_nxt  = col[jn];
        float el_nxt = el[(size_t)u_nxt * 4 + head];
        u16x8 hv_nxt = *reinterpret_cast<const u16x8*>(&hb[(size_t)u_nxt * 128 + f0]);

        float e = leaky02(el_cur + erq);
        float d = e - mref;
        if (__builtin_expect(d > 50.f, 0)) {   // almost never taken
            float scl = __expf(-d);            // exp(mref - e)
            s *= scl;
#pragma unroll
            for (int k = 0; k < 8; ++k) acc[k] *= scl;
            mref = e;
            d = 0.f;
        }
        float p = __expf(d);
        s += p;
#pragma unroll
        for (int k = 0; k < 8; ++k) acc[k] += p * bf2f(hv_cur[k]);

        el_cur = el_nxt; hv_cur = hv_nxt;
    }
    const float is = 1.f / s;

    float4 b0 = *reinterpret_cast<const float4*>(&bias[f0]);
    float4 b1 = *reinterpret_cast<const float4*>(&bias[f0 + 4]);
    const float bb[8] = {b0.x, b0.y, b0.z, b0.w, b1.x, b1.y, b1.z, b1.w};

    if (last) {
        float4 p0 = *reinterpret_cast<const float4*>(&pW[f0]);
        float4 p1 = *reinterpret_cast<const float4*>(&pW[f0 + 4]);
        const float pp[8] = {p0.x, p0.y, p0.z, p0.w, p1.x, p1.y, p1.z, p1.w};
        float part = 0.f;
#pragma unroll
        for (int k = 0; k < 8; ++k) part += (acc[k] * is + bb[k]) * pp[k];
#pragma unroll
        for (int d = 1; d <= 8; d <<= 1) part += __shfl_xor(part, d, 64);
        if (l16 == 0) logits[v] = part + pb[0];
    } else {
        u16x8 o;
#pragma unroll
        for (int k = 0; k < 8; ++k) o[k] = f2bf(leaky01(acc[k] * is + bb[k]));
        *reinterpret_cast<u16x8*>(&xout[(size_t)v * 128 + f0]) = o;
    }
}

// ---------------------------------------------------------------------------
extern "C" void kernel_launch(void* const* d_in, const int* in_sizes, int n_in,
                              void* d_out, int out_size, void* d_ws, size_t ws_size,
                              hipStream_t stream)
{
    const float* weights = (const float*)d_in[0];
    const float* lin_W   = (const float*)d_in[1];
    const float* lin_b   = (const float*)d_in[2];
    const float* fc_W    = (const float*)d_in[3];
    const float* attn_l  = (const float*)d_in[4];
    const float* attn_r  = (const float*)d_in[5];
    const float* conv_b  = (const float*)d_in[6];
    const float* pred_W  = (const float*)d_in[7];
    const float* pred_b  = (const float*)d_in[8];
    const int*   src     = (const int*)d_in[9];
    const int*   dst     = (const int*)d_in[10];

    const int N = in_sizes[0];
    const int E = in_sizes[9];
    const int NB = (N + SCAN_TILE - 1) / SCAN_TILE;

    // workspace layout (16B-aligned sections)
    unsigned short* xb = (unsigned short*)d_ws;                    // N*128 bf16 (pre-activated)
    unsigned short* hb = xb + (size_t)N * 128;                     // N*128 bf16
    float* el  = (float*)(hb + (size_t)N * 128);                   // N*4
    float* er  = el + (size_t)N * 4;                               // N*4
    float* c1  = er + (size_t)N * 4;                               // 128
    float* c2  = c1 + 128;                                         // 128
    float* prm = c2 + 128;                                         // 16
    short* Whs = (short*)(prm + 16);                               // 2*16384 bf16 (packed)
    short* Wls = Whs + 2 * 16384;                                  // 2*16384 bf16 (packed)
    short* Mhs = Wls + 2 * 16384;                                  // 2*2048 bf16 (Mext hi)
    short* Mls = Mhs + 2 * 2048;                                   // 2*2048 bf16 (Mext lo)
    int*   deg  = (int*)(Mls + 2 * 2048);                          // N
    int*   rowp = deg + N;                                         // N+1
    int*   slot = rowp + (N + 1);                                  // E
    int*   col  = slot + E;                                        // E+N
    int*   bsum = col + (E + N);                                   // NB
    int*   bpre = bsum + NB;                                       // NB

    // CSR build + packed W split (fresh every call: ws is re-poisoned)
    init_split_kernel<<<(N + 255) / 256, 256, 0, stream>>>(
        deg, N, fc_W + 16384, Whs, Wls, 2 * 16384);
    mlr_prep_kernel<<<2, 128, 0, stream>>>(fc_W, attn_l, attn_r, Mhs, Mls);
    deg_count_slot_kernel<<<(E + 255) / 256, 256, 0, stream>>>(dst, deg, slot, E);
    scanA_kernel<<<NB, 256, 0, stream>>>(deg, bsum, N);
    scanB_kernel<<<1, 1024, 0, stream>>>(bsum, bpre, rowp, NB, N);
    scanC_kernel<<<NB, 256, 0, stream>>>(deg, bpre, rowp, col, N);
    scatter2_kernel<<<(E + 255) / 256, 256, 0, stream>>>(src, dst, slot, rowp, col, E);

    // Layer 0 via rank-1 identity
    rank1_prep_kernel<<<1, 128, 0, stream>>>(lin_W, lin_b, fc_W, attn_l, attn_r,
                                             c1, c2, prm);
    rank1_apply_kernel<<<((size_t)N * 32 + 255) / 256, 256, 0, stream>>>(
        weights, c1, c2, prm, hb, el, er, N);
    agg_fused_kernel<<<(N + 15) / 16, 256, 0, stream>>>(
        hb, el, er, rowp, col, conv_b, xb, pred_W, pred_b, (float*)d_out, N, 0);

    // Layers 1, 2 (MFMA bf16 gemm, 32 rows/wave, packed W, fused el/er)
    for (int l = 1; l < 3; ++l) {
        gemm_mfma_kernel<<<(N + 127) / 128, 256, 0, stream>>>(
            xb, Whs + (size_t)(l - 1) * 16384, Wls + (size_t)(l - 1) * 16384,
            Mhs + (size_t)(l - 1) * 2048, Mls + (size_t)(l - 1) * 2048,
            hb, el, er, N);
        agg_fused_kernel<<<(N + 15) / 16, 256, 0, stream>>>(
            hb, el, er, rowp, col, conv_b + l * 128, xb, pred_W, pred_b,
            (float*)d_out, N, l == 2 ? 1 : 0);
    }
}

// Round 3
// 309.846 us; speedup vs baseline: 1.2144x; 1.1569x over previous
//
#include <hip/hip_runtime.h>
#include <hip/hip_bf16.h>
#include <math.h>

// Problem constants: N=100000, E=600000, D=128, H=4, F=32, L=3

__device__ __forceinline__ float leaky02(float x) {
    return x >= 0.f ? x : 0.2f * x;
}
__device__ __forceinline__ float leaky01(float x) {
    return x >= 0.f ? x : 0.01f * x;
}

// bf16 helpers (round-to-nearest-even)
__device__ __forceinline__ unsigned short f2bf(float f) {
    unsigned u = __float_as_uint(f);
    unsigned r = u + 0x7FFFu + ((u >> 16) & 1u);
    return (unsigned short)(r >> 16);
}
__device__ __forceinline__ float bf2f(unsigned short s) {
    return __uint_as_float(((unsigned)s) << 16);
}

typedef __attribute__((ext_vector_type(8))) short bf16x8;
typedef __attribute__((ext_vector_type(8))) unsigned short u16x8;
typedef __attribute__((ext_vector_type(4))) float f32x4;

// ---------------------------------------------------------------------------
// Fused init: deg[i]=1 + W split into bf16 hi/lo, PACKED IN FRAGMENT ORDER.
__global__ __launch_bounds__(256) void init_split_kernel(
    int* __restrict__ deg, int N, const float* __restrict__ W,
    short* __restrict__ Wh, short* __restrict__ Wl, int n)
{
    int i = blockIdx.x * 256 + threadIdx.x;
    if (i < N) deg[i] = 1;
    if (i < n) {
        int l    = i >> 14;          // layer (0,1)
        int p    = i & 16383;
        int j    = p & 7;
        int lane = (p >> 3) & 63;
        int c    = (p >> 9) & 7;
        int kk   = p >> 12;
        int mr   = lane & 15;
        int quad = lane >> 4;
        int row  = c * 16 + mr;
        int d    = kk * 32 + quad * 8 + j;
        float f = W[(size_t)l * 16384 + row * 128 + d];
        unsigned short hi = f2bf(f);
        Wh[i] = (short)hi;
        Wl[i] = (short)f2bf(f - bf2f(hi));
    }
}

// Mext[r][d] per layer: r 0..3 = Wt@Al head r, r 4..7 = Wt@Ar, r 8..15 = 0.
__global__ __launch_bounds__(128) void mlr_prep_kernel(
    const float* __restrict__ fc_W, const float* __restrict__ attn_l,
    const float* __restrict__ attn_r, short* __restrict__ Mh,
    short* __restrict__ Ml)
{
    int l = blockIdx.x;                       // 0,1 -> layers 1,2
    const float* W  = fc_W + (size_t)(l + 1) * 16384;
    const float* al = attn_l + (l + 1) * 128;
    const float* ar = attn_r + (l + 1) * 128;
    short* mh = Mh + (size_t)l * 16 * 128;
    short* ml = Ml + (size_t)l * 16 * 128;
    int d = threadIdx.x;
#pragma unroll
    for (int r = 0; r < 8; ++r) {
        int hh = r & 3;
        const float* av = (r < 4) ? al : ar;
        float s = 0.f;
        for (int f = 0; f < 32; ++f)
            s += W[(size_t)(hh * 32 + f) * 128 + d] * av[hh * 32 + f];
        unsigned short hi = f2bf(s);
        mh[r * 128 + d] = (short)hi;
        ml[r * 128 + d] = (short)f2bf(s - bf2f(hi));
    }
#pragma unroll
    for (int r = 8; r < 16; ++r) { mh[r * 128 + d] = 0; ml[r * 128 + d] = 0; }
}

// slot[i] = old count (>=1 because self loop holds slot 0)
__global__ __launch_bounds__(256) void deg_count_slot_kernel(
    const int* __restrict__ dst, int* __restrict__ deg,
    int* __restrict__ slot, int E)
{
    int i = blockIdx.x * 256 + threadIdx.x;
    if (i < E) slot[i] = atomicAdd(&deg[dst[i]], 1);
}

#define SCAN_TILE 1024

__global__ __launch_bounds__(256) void scanA_kernel(
    const int* __restrict__ deg, int* __restrict__ bsum, int N)
{
    __shared__ int ws[4];
    int b = blockIdx.x, t = threadIdx.x;
    int base = b * SCAN_TILE + t * 4;
    int s = 0;
#pragma unroll
    for (int k = 0; k < 4; ++k) {
        int i = base + k;
        if (i < N) s += deg[i];
    }
#pragma unroll
    for (int m = 32; m >= 1; m >>= 1) s += __shfl_xor(s, m, 64);
    if ((t & 63) == 0) ws[t >> 6] = s;
    __syncthreads();
    if (t == 0) bsum[b] = ws[0] + ws[1] + ws[2] + ws[3];
}

__global__ __launch_bounds__(1024) void scanB_kernel(
    int* __restrict__ bsum, int* __restrict__ bpre, int* __restrict__ rowp,
    int NB, int N)
{
    __shared__ int sh[1024];
    int t = threadIdx.x;
    int v = (t < NB) ? bsum[t] : 0;
    sh[t] = v;
    __syncthreads();
    for (int off = 1; off < 1024; off <<= 1) {
        int u = (t >= off) ? sh[t - off] : 0;
        __syncthreads();
        sh[t] += u;
        __syncthreads();
    }
    if (t < NB) bpre[t] = sh[t] - v;          // exclusive prefix
    if (t == 1023) rowp[N] = sh[1023];        // total
}

// scanC also writes the self-loop entry: col[rowp[i]] = i (slot 0).
__global__ __launch_bounds__(256) void scanC_kernel(
    const int* __restrict__ deg, const int* __restrict__ bpre,
    int* __restrict__ rowp, int* __restrict__ col, int N)
{
    __shared__ int sh[256];
    int b = blockIdx.x, t = threadIdx.x;
    int base = b * SCAN_TILE + t * 4;
    int v[4];
#pragma unroll
    for (int k = 0; k < 4; ++k) {
        int i = base + k;
        v[k] = (i < N) ? deg[i] : 0;
    }
    int tsum = v[0] + v[1] + v[2] + v[3];
    sh[t] = tsum;
    __syncthreads();
    for (int off = 1; off < 256; off <<= 1) {
        int u = (t >= off) ? sh[t - off] : 0;
        __syncthreads();
        sh[t] += u;
        __syncthreads();
    }
    int pre = bpre[b] + sh[t] - tsum;
#pragma unroll
    for (int k = 0; k < 4; ++k) {
        int i = base + k;
        if (i < N) {
            rowp[i] = pre;
            col[pre] = i;   // self loop at slot 0
        }
        pre += v[k];
    }
}

// atomic-free scatter: position fully determined by rowp + recorded slot
__global__ __launch_bounds__(256) void scatter2_kernel(
    const int* __restrict__ src, const int* __restrict__ dst,
    const int* __restrict__ slot, const int* __restrict__ rowp,
    int* __restrict__ col, int E)
{
    int i = blockIdx.x * 256 + threadIdx.x;
    if (i < E) col[rowp[dst[i]] + slot[i]] = src[i];
}

// ---------------------------------------------------------------------------
// Layer-0 rank-1 precompute + layer-2 epilogue constant C = sum(b2*pW)+pb.
__global__ __launch_bounds__(128) void rank1_prep_kernel(
    const float* __restrict__ lW, const float* __restrict__ lb,
    const float* __restrict__ W0, const float* __restrict__ al,
    const float* __restrict__ ar, const float* __restrict__ cb2,
    const float* __restrict__ pW, const float* __restrict__ pb,
    float* __restrict__ c1, float* __restrict__ c2, float* __restrict__ prm)
{
    int j = threadIdx.x;
    float s1 = 0.f, s2 = 0.f;
    for (int d = 0; d < 128; ++d) {
        float wv = W0[j * 128 + d];
        s1 += lW[d] * wv;
        s2 += lb[d] * wv;
    }
    c1[j] = s1; c2[j] = s2;
    __shared__ float sh1[128], sh2[128], sh3[128], sh4[128], sh5[128];
    sh1[j] = s1 * al[j]; sh2[j] = s2 * al[j];
    sh3[j] = s1 * ar[j]; sh4[j] = s2 * ar[j];
    sh5[j] = cb2[j] * pW[j];
    __syncthreads();
    if (j < 4) {
        float p = 0.f, q = 0.f, r = 0.f, s = 0.f;
        for (int f = 0; f < 32; ++f) {
            p += sh1[j * 32 + f]; q += sh2[j * 32 + f];
            r += sh3[j * 32 + f]; s += sh4[j * 32 + f];
        }
        prm[j] = p; prm[4 + j] = q; prm[8 + j] = r; prm[12 + j] = s;
    }
    if (j == 0) {
        float cs = 0.f;
        for (int k = 0; k < 128; ++k) cs += sh5[k];
        prm[16] = cs + pb[0];
    }
}

// ---------------------------------------------------------------------------
// LAYER-0 aggregation via rank-1 identity: h0[u] = w[u]*c1 + c2, so
// sum_u p*h0[u] = (sum p*w_u)*c1 + (sum p)*c2. Per-edge gather is ONLY
// w[u] (4B; 400KB array -> per-XCD-L2-resident) and el0[u] = w_u*pl+ql
// is computed in-register. Replaces rank1_apply + the fat layer-0 agg.
__global__ __launch_bounds__(256) void agg0_kernel(
    const float* __restrict__ w, const float* __restrict__ c1,
    const float* __restrict__ c2, const float* __restrict__ prm,
    const int* __restrict__ rowp, const int* __restrict__ col,
    const float* __restrict__ bias, unsigned short* __restrict__ xout, int N)
{
    const int lane = threadIdx.x & 63;
    const int q    = lane >> 4;
    const int l16  = lane & 15;
    const int v    = blockIdx.x * 16 + (threadIdx.x >> 6) * 4 + q;
    if (v >= N) return;

    const int r0 = rowp[v], r1 = rowp[v + 1];
    const int head = l16 >> 2;
    const int f0   = l16 * 8;
    const float pl = prm[head],     ql = prm[4 + head];
    const float pr = prm[8 + head], qr = prm[12 + head];

    const float wv  = w[v];
    const float erq = wv * pr + qr;
    const float mref = leaky02(wv * pl + ql + erq);   // self-loop e

    float S = 0.f, Sw = 0.f;
    float w_cur = wv;                                  // col[r0] == v
    for (int j = r0; j < r1; ++j) {
        int jn = (j + 1 < r1) ? (j + 1) : j;
        float w_nxt = w[col[jn]];

        float e = leaky02(w_cur * pl + ql + erq);
        float d = fminf(e - mref, 80.f);
        float p = __expf(d);
        S += p; Sw += p * w_cur;
        w_cur = w_nxt;
    }
    const float t = Sw / S;

    float4 a0 = *reinterpret_cast<const float4*>(&c1[f0]);
    float4 a1 = *reinterpret_cast<const float4*>(&c1[f0 + 4]);
    float4 g0 = *reinterpret_cast<const float4*>(&c2[f0]);
    float4 g1 = *reinterpret_cast<const float4*>(&c2[f0 + 4]);
    float4 b0 = *reinterpret_cast<const float4*>(&bias[f0]);
    float4 b1 = *reinterpret_cast<const float4*>(&bias[f0 + 4]);
    const float aa[8] = {a0.x, a0.y, a0.z, a0.w, a1.x, a1.y, a1.z, a1.w};
    const float gg[8] = {g0.x, g0.y, g0.z, g0.w, g1.x, g1.y, g1.z, g1.w};
    const float bb[8] = {b0.x, b0.y, b0.z, b0.w, b1.x, b1.y, b1.z, b1.w};

    u16x8 o;
#pragma unroll
    for (int k = 0; k < 8; ++k)
        o[k] = f2bf(leaky01(t * aa[k] + gg[k] + bb[k]));
    *reinterpret_cast<u16x8*>(&xout[(size_t)v * 128 + f0]) = o;
}

// ---------------------------------------------------------------------------
// MFMA bf16 GEMM (layers 1,2) + fused el/er tile — 32 rows/wave,
// FRAGMENT-PACKED W. mode 0 (layer1): write hb + el + er.
// mode 1 (layer2): skip hb; write yel[row*8+h*2] = {y_h = h.pW_h, el_h}
// (float2 per head, 3.2MB array -> L2-resident for the last agg) + er.
__global__ __launch_bounds__(256) void gemm_mfma_kernel(
    const unsigned short* __restrict__ xb, const short* __restrict__ Wh,
    const short* __restrict__ Wl, const short* __restrict__ Mh,
    const short* __restrict__ Ml, unsigned short* __restrict__ hb,
    float* __restrict__ el, float* __restrict__ er,
    const float* __restrict__ pW, float* __restrict__ yel,
    int N, int mode)
{
    const int lane = threadIdx.x & 63;
    const int wv   = threadIdx.x >> 6;
    const int m0   = blockIdx.x * 128 + wv * 32;  // 32 rows per wave
    const int mr   = lane & 15;
    const int quad = lane >> 4;

    int r0 = m0 + mr;      if (r0 > N - 1) r0 = N - 1;   // clamped load rows
    int r1 = m0 + 16 + mr; if (r1 > N - 1) r1 = N - 1;
    const unsigned short* xp0 = xb + (size_t)r0 * 128 + quad * 8;
    const unsigned short* xp1 = xb + (size_t)r1 * 128 + quad * 8;

    f32x4 acc0[8], acc1[8], acce0, acce1;
#pragma unroll
    for (int c = 0; c < 8; ++c) {
        acc0[c] = (f32x4){0.f, 0.f, 0.f, 0.f};
        acc1[c] = (f32x4){0.f, 0.f, 0.f, 0.f};
    }
    acce0 = (f32x4){0.f, 0.f, 0.f, 0.f};
    acce1 = (f32x4){0.f, 0.f, 0.f, 0.f};

#pragma unroll
    for (int kk = 0; kk < 4; ++kk) {
        bf16x8 a0 = *reinterpret_cast<const bf16x8*>(xp0 + kk * 32);
        bf16x8 a1 = *reinterpret_cast<const bf16x8*>(xp1 + kk * 32);

        const int kb = kk * 32 + quad * 8;
        bf16x8 bh[8], bl[8];
#pragma unroll
        for (int c = 0; c < 8; ++c) {
            const size_t wo = (size_t)((kk * 8 + c) * 64 + lane) * 8;
            bh[c] = *reinterpret_cast<const bf16x8*>(Wh + wo);
            bl[c] = *reinterpret_cast<const bf16x8*>(Wl + wo);
        }
        bf16x8 eh = *reinterpret_cast<const bf16x8*>(Mh + (size_t)mr * 128 + kb);
        bf16x8 eo = *reinterpret_cast<const bf16x8*>(Ml + (size_t)mr * 128 + kb);
#pragma unroll
        for (int c = 0; c < 8; ++c) {
            acc0[c] = __builtin_amdgcn_mfma_f32_16x16x32_bf16(a0, bh[c], acc0[c], 0, 0, 0);
            acc0[c] = __builtin_amdgcn_mfma_f32_16x16x32_bf16(a0, bl[c], acc0[c], 0, 0, 0);
            acc1[c] = __builtin_amdgcn_mfma_f32_16x16x32_bf16(a1, bh[c], acc1[c], 0, 0, 0);
            acc1[c] = __builtin_amdgcn_mfma_f32_16x16x32_bf16(a1, bl[c], acc1[c], 0, 0, 0);
        }
        acce0 = __builtin_amdgcn_mfma_f32_16x16x32_bf16(a0, eh, acce0, 0, 0, 0);
        acce0 = __builtin_amdgcn_mfma_f32_16x16x32_bf16(a0, eo, acce0, 0, 0, 0);
        acce1 = __builtin_amdgcn_mfma_f32_16x16x32_bf16(a1, eh, acce1, 0, 0, 0);
        acce1 = __builtin_amdgcn_mfma_f32_16x16x32_bf16(a1, eo, acce1, 0, 0, 0);
    }

    if (mode == 0) {
#pragma unroll
        for (int i = 0; i < 4; ++i) {
            int rowA = m0 + quad * 4 + i;
            if (rowA < N) {
                unsigned short* hp = hb + (size_t)rowA * 128 + mr;
#pragma unroll
                for (int c = 0; c < 8; ++c) hp[c * 16] = f2bf(acc0[c][i]);
                if (mr < 4)       el[(size_t)rowA * 4 + mr]       = acce0[i];
                else if (mr < 8)  er[(size_t)rowA * 4 + (mr - 4)] = acce0[i];
            }
            int rowB = m0 + 16 + quad * 4 + i;
            if (rowB < N) {
                unsigned short* hp = hb + (size_t)rowB * 128 + mr;
#pragma unroll
                for (int c = 0; c < 8; ++c) hp[c * 16] = f2bf(acc1[c][i]);
                if (mr < 4)       el[(size_t)rowB * 4 + mr]       = acce1[i];
                else if (mr < 8)  er[(size_t)rowB * 4 + (mr - 4)] = acce1[i];
            }
        }
    } else {
        // y_h = sum_f h[row, 32h..32h+31] * pW[...]; feature f = mr + c*16
        float pw[8];
#pragma unroll
        for (int c = 0; c < 8; ++c) pw[c] = pW[mr + c * 16];
#pragma unroll
        for (int i = 0; i < 4; ++i) {
            int rowA = m0 + quad * 4 + i;
            {
                float y[4];
#pragma unroll
                for (int h = 0; h < 4; ++h)
                    y[h] = acc0[2 * h][i] * pw[2 * h] + acc0[2 * h + 1][i] * pw[2 * h + 1];
#pragma unroll
                for (int d = 1; d < 16; d <<= 1) {
#pragma unroll
                    for (int h = 0; h < 4; ++h) y[h] += __shfl_xor(y[h], d, 64);
                }
                if (rowA < N) {
                    if (mr < 4) {
                        float2 o; o.x = y[mr]; o.y = acce0[i];
                        *reinterpret_cast<float2*>(&yel[(size_t)rowA * 8 + mr * 2]) = o;
                    } else if (mr < 8) {
                        er[(size_t)rowA * 4 + (mr - 4)] = acce0[i];
                    }
                }
            }
            int rowB = m0 + 16 + quad * 4 + i;
            {
                float y[4];
#pragma unroll
                for (int h = 0; h < 4; ++h)
                    y[h] = acc1[2 * h][i] * pw[2 * h] + acc1[2 * h + 1][i] * pw[2 * h + 1];
#pragma unroll
                for (int d = 1; d < 16; d <<= 1) {
#pragma unroll
                    for (int h = 0; h < 4; ++h) y[h] += __shfl_xor(y[h], d, 64);
                }
                if (rowB < N) {
                    if (mr < 4) {
                        float2 o; o.x = y[mr]; o.y = acce1[i];
                        *reinterpret_cast<float2*>(&yel[(size_t)rowB * 8 + mr * 2]) = o;
                    } else if (mr < 8) {
                        er[(size_t)rowB * 4 + (mr - 4)] = acce1[i];
                    }
                }
            }
        }
    }
}

// ---------------------------------------------------------------------------
// MIDDLE-layer aggregation (full 256B h-row gather — irreducible) with
// fixed-reference defer-max, branchless clamp (d>80 never occurs; if it
// did, e^80*deg < 1e36 stays in f32 range).
__global__ __launch_bounds__(256) void agg_mid_kernel(
    const unsigned short* __restrict__ hb, const float* __restrict__ el,
    const float* __restrict__ er, const int* __restrict__ rowp,
    const int* __restrict__ col, const float* __restrict__ bias,
    unsigned short* __restrict__ xout, int N)
{
    const int lane = threadIdx.x & 63;
    const int q    = lane >> 4;
    const int l16  = lane & 15;
    const int v    = blockIdx.x * 16 + (threadIdx.x >> 6) * 4 + q;
    if (v >= N) return;

    const int r0 = rowp[v], r1 = rowp[v + 1];
    const int head = l16 >> 2;
    const int f0   = l16 * 8;
    const float erq = er[(size_t)v * 4 + head];
    const float el_self = el[(size_t)v * 4 + head];
    const float mref = leaky02(el_self + erq);

    float s = 0.f;
    float acc[8];
#pragma unroll
    for (int k = 0; k < 8; ++k) acc[k] = 0.f;

    float el_cur = el_self;                    // col[r0] == v
    u16x8 hv_cur = *reinterpret_cast<const u16x8*>(&hb[(size_t)v * 128 + f0]);

    for (int j = r0; j < r1; ++j) {
        int jn = (j + 1 < r1) ? (j + 1) : j;
        int   u_nxt  = col[jn];
        float el_nxt = el[(size_t)u_nxt * 4 + head];
        u16x8 hv_nxt = *reinterpret_cast<const u16x8*>(&hb[(size_t)u_nxt * 128 + f0]);

        float e = leaky02(el_cur + erq);
        float d = fminf(e - mref, 80.f);
        float p = __expf(d);
        s += p;
#pragma unroll
        for (int k = 0; k < 8; ++k) acc[k] += p * bf2f(hv_cur[k]);

        el_cur = el_nxt; hv_cur = hv_nxt;
    }
    const float is = 1.f / s;

    float4 b0 = *reinterpret_cast<const float4*>(&bias[f0]);
    float4 b1 = *reinterpret_cast<const float4*>(&bias[f0 + 4]);
    const float bb[8] = {b0.x, b0.y, b0.z, b0.w, b1.x, b1.y, b1.z, b1.w};

    u16x8 o;
#pragma unroll
    for (int k = 0; k < 8; ++k) o[k] = f2bf(leaky01(acc[k] * is + bb[k]));
    *reinterpret_cast<u16x8*>(&xout[(size_t)v * 128 + f0]) = o;
}

// ---------------------------------------------------------------------------
// LAST-layer aggregation: logits[v] = sum_h (sum_u p*y_uh)/S_h + C.
// Gathers only yel {y,el} float2 per (u,head) — 3.2MB array, L2-resident.
__global__ __launch_bounds__(256) void agg2_kernel(
    const float* __restrict__ yel, const float* __restrict__ er,
    const int* __restrict__ rowp, const int* __restrict__ col,
    const float* __restrict__ prm, float* __restrict__ logits, int N)
{
    const int lane = threadIdx.x & 63;
    const int q    = lane >> 4;
    const int l16  = lane & 15;
    const int v    = blockIdx.x * 16 + (threadIdx.x >> 6) * 4 + q;
    if (v >= N) return;

    const int r0 = rowp[v], r1 = rowp[v + 1];
    const int head = l16 >> 2;
    const float erq = er[(size_t)v * 4 + head];

    float2 cur = *reinterpret_cast<const float2*>(&yel[(size_t)v * 8 + head * 2]);
    const float mref = leaky02(cur.y + erq);   // self-loop e (col[r0]==v)

    float S = 0.f, A = 0.f;
    for (int j = r0; j < r1; ++j) {
        int jn = (j + 1 < r1) ? (j + 1) : j;
        int u = col[jn];
        float2 nxt = *reinterpret_cast<const float2*>(&yel[(size_t)u * 8 + head * 2]);

        float e = leaky02(cur.y + erq);
        float d = fminf(e - mref, 80.f);
        float p = __expf(d);
        S += p; A += p * cur.x;
        cur = nxt;
    }
    float part = A / S;
    part += __shfl_xor(part, 4, 64);
    part += __shfl_xor(part, 8, 64);
    if (l16 == 0) logits[v] = part + prm[16];
}

// ---------------------------------------------------------------------------
extern "C" void kernel_launch(void* const* d_in, const int* in_sizes, int n_in,
                              void* d_out, int out_size, void* d_ws, size_t ws_size,
                              hipStream_t stream)
{
    const float* weights = (const float*)d_in[0];
    const float* lin_W   = (const float*)d_in[1];
    const float* lin_b   = (const float*)d_in[2];
    const float* fc_W    = (const float*)d_in[3];
    const float* attn_l  = (const float*)d_in[4];
    const float* attn_r  = (const float*)d_in[5];
    const float* conv_b  = (const float*)d_in[6];
    const float* pred_W  = (const float*)d_in[7];
    const float* pred_b  = (const float*)d_in[8];
    const int*   src     = (const int*)d_in[9];
    const int*   dst     = (const int*)d_in[10];

    const int N = in_sizes[0];
    const int E = in_sizes[9];
    const int NB = (N + SCAN_TILE - 1) / SCAN_TILE;

    // workspace layout (16B-aligned sections)
    unsigned short* xb = (unsigned short*)d_ws;                    // N*128 bf16 (pre-activated)
    unsigned short* hb = xb + (size_t)N * 128;                     // N*128 bf16
    float* el  = (float*)(hb + (size_t)N * 128);                   // N*4
    float* er  = el + (size_t)N * 4;                               // N*4
    float* yel = er + (size_t)N * 4;                               // N*8 {y,el} per head
    float* c1  = yel + (size_t)N * 8;                              // 128
    float* c2  = c1 + 128;                                         // 128
    float* prm = c2 + 128;                                         // 32
    short* Whs = (short*)(prm + 32);                               // 2*16384 bf16 (packed)
    short* Wls = Whs + 2 * 16384;                                  // 2*16384 bf16 (packed)
    short* Mhs = Wls + 2 * 16384;                                  // 2*2048 bf16 (Mext hi)
    short* Mls = Mhs + 2 * 2048;                                   // 2*2048 bf16 (Mext lo)
    int*   deg  = (int*)(Mls + 2 * 2048);                          // N
    int*   rowp = deg + N;                                         // N+1
    int*   slot = rowp + (N + 1);                                  // E
    int*   col  = slot + E;                                        // E+N
    int*   bsum = col + (E + N);                                   // NB
    int*   bpre = bsum + NB;                                       // NB

    // CSR build + packed W split (fresh every call: ws is re-poisoned)
    init_split_kernel<<<(N + 255) / 256, 256, 0, stream>>>(
        deg, N, fc_W + 16384, Whs, Wls, 2 * 16384);
    mlr_prep_kernel<<<2, 128, 0, stream>>>(fc_W, attn_l, attn_r, Mhs, Mls);
    deg_count_slot_kernel<<<(E + 255) / 256, 256, 0, stream>>>(dst, deg, slot, E);
    scanA_kernel<<<NB, 256, 0, stream>>>(deg, bsum, N);
    scanB_kernel<<<1, 1024, 0, stream>>>(bsum, bpre, rowp, NB, N);
    scanC_kernel<<<NB, 256, 0, stream>>>(deg, bpre, rowp, col, N);
    scatter2_kernel<<<(E + 255) / 256, 256, 0, stream>>>(src, dst, slot, rowp, col, E);

    rank1_prep_kernel<<<1, 128, 0, stream>>>(
        lin_W, lin_b, fc_W, attn_l, attn_r, conv_b + 2 * 128, pred_W, pred_b,
        c1, c2, prm);

    // Layer 0: rank-1 aggregation straight from w (no h0 materialization)
    agg0_kernel<<<(N + 15) / 16, 256, 0, stream>>>(
        weights, c1, c2, prm, rowp, col, conv_b, xb, N);

    // Layer 1: gemm (mode 0) + full-gather aggregation
    gemm_mfma_kernel<<<(N + 127) / 128, 256, 0, stream>>>(
        xb, Whs, Wls, Mhs, Mls, hb, el, er, pred_W, yel, N, 0);
    agg_mid_kernel<<<(N + 15) / 16, 256, 0, stream>>>(
        hb, el, er, rowp, col, conv_b + 128, xb, N);

    // Layer 2: gemm (mode 1: y=h.pW + el packed) + light aggregation
    gemm_mfma_kernel<<<(N + 127) / 128, 256, 0, stream>>>(
        xb, Whs + 16384, Wls + 16384, Mhs + 2048, Mls + 2048,
        hb, el, er, pred_W, yel, N, 1);
    agg2_kernel<<<(N + 15) / 16, 256, 0, stream>>>(
        yel, er, rowp, col, prm, (float*)d_out, N);
}

// Round 4
// 274.967 us; speedup vs baseline: 1.3685x; 1.1268x over previous
//
#include <hip/hip_runtime.h>
#include <hip/hip_bf16.h>
#include <math.h>

// Problem constants: N=100000, E=600000, D=128, H=4, F=32, L=3

__device__ __forceinline__ float leaky02(float x) {
    return x >= 0.f ? x : 0.2f * x;
}
__device__ __forceinline__ float leaky01(float x) {
    return x >= 0.f ? x : 0.01f * x;
}

// bf16 helpers (round-to-nearest-even)
__device__ __forceinline__ unsigned short f2bf(float f) {
    unsigned u = __float_as_uint(f);
    unsigned r = u + 0x7FFFu + ((u >> 16) & 1u);
    return (unsigned short)(r >> 16);
}
__device__ __forceinline__ float bf2f(unsigned short s) {
    return __uint_as_float(((unsigned)s) << 16);
}

typedef __attribute__((ext_vector_type(8))) short bf16x8;
typedef __attribute__((ext_vector_type(8))) unsigned short u16x8;
typedef __attribute__((ext_vector_type(4))) float f32x4;

// ---------------------------------------------------------------------------
// Fused init: deg[i]=1 + W split into bf16 hi/lo, PACKED IN FRAGMENT ORDER.
__global__ __launch_bounds__(256) void init_split_kernel(
    int* __restrict__ deg, int N, const float* __restrict__ W,
    short* __restrict__ Wh, short* __restrict__ Wl, int n)
{
    int i = blockIdx.x * 256 + threadIdx.x;
    if (i < N) deg[i] = 1;
    if (i < n) {
        int l    = i >> 14;          // layer (0,1)
        int p    = i & 16383;
        int j    = p & 7;
        int lane = (p >> 3) & 63;
        int c    = (p >> 9) & 7;
        int kk   = p >> 12;
        int mr   = lane & 15;
        int quad = lane >> 4;
        int row  = c * 16 + mr;
        int d    = kk * 32 + quad * 8 + j;
        float f = W[(size_t)l * 16384 + row * 128 + d];
        unsigned short hi = f2bf(f);
        Wh[i] = (short)hi;
        Wl[i] = (short)f2bf(f - bf2f(hi));
    }
}

// Mext[r][d] per layer — PARALLELIZED: one thread per (r,d) output element
// (was 2x128 threads with 256 scattered loads each -> 43us latency-bound;
// now 2x1024 threads x 32 coalesced loads each).
__global__ __launch_bounds__(1024) void mlr_prep_kernel(
    const float* __restrict__ fc_W, const float* __restrict__ attn_l,
    const float* __restrict__ attn_r, short* __restrict__ Mh,
    short* __restrict__ Ml)
{
    int l = blockIdx.x;                       // 0,1 -> layers 1,2
    const float* W  = fc_W + (size_t)(l + 1) * 16384;
    const float* al = attn_l + (l + 1) * 128;
    const float* ar = attn_r + (l + 1) * 128;
    short* mh = Mh + (size_t)l * 16 * 128;
    short* ml = Ml + (size_t)l * 16 * 128;
    int t = threadIdx.x;
    int r = t >> 7;                           // 0..7
    int d = t & 127;
    int hh = r & 3;
    const float* av = (r < 4) ? al : ar;
    float s = 0.f;
#pragma unroll
    for (int f = 0; f < 32; ++f)
        s += W[(size_t)(hh * 32 + f) * 128 + d] * av[hh * 32 + f];
    unsigned short hi = f2bf(s);
    mh[r * 128 + d] = (short)hi;
    ml[r * 128 + d] = (short)f2bf(s - bf2f(hi));
    mh[(r + 8) * 128 + d] = 0;                // zero rows 8..15
    ml[(r + 8) * 128 + d] = 0;
}

// slot[i] = old count (>=1 because self loop holds slot 0)
__global__ __launch_bounds__(256) void deg_count_slot_kernel(
    const int* __restrict__ dst, int* __restrict__ deg,
    int* __restrict__ slot, int E)
{
    int i = blockIdx.x * 256 + threadIdx.x;
    if (i < E) slot[i] = atomicAdd(&deg[dst[i]], 1);
}

#define SCAN_TILE 1024

__global__ __launch_bounds__(256) void scanA_kernel(
    const int* __restrict__ deg, int* __restrict__ bsum, int N)
{
    __shared__ int ws[4];
    int b = blockIdx.x, t = threadIdx.x;
    int base = b * SCAN_TILE + t * 4;
    int s = 0;
#pragma unroll
    for (int k = 0; k < 4; ++k) {
        int i = base + k;
        if (i < N) s += deg[i];
    }
#pragma unroll
    for (int m = 32; m >= 1; m >>= 1) s += __shfl_xor(s, m, 64);
    if ((t & 63) == 0) ws[t >> 6] = s;
    __syncthreads();
    if (t == 0) bsum[b] = ws[0] + ws[1] + ws[2] + ws[3];
}

__global__ __launch_bounds__(1024) void scanB_kernel(
    int* __restrict__ bsum, int* __restrict__ bpre, int* __restrict__ rowp,
    int NB, int N)
{
    __shared__ int sh[1024];
    int t = threadIdx.x;
    int v = (t < NB) ? bsum[t] : 0;
    sh[t] = v;
    __syncthreads();
    for (int off = 1; off < 1024; off <<= 1) {
        int u = (t >= off) ? sh[t - off] : 0;
        __syncthreads();
        sh[t] += u;
        __syncthreads();
    }
    if (t < NB) bpre[t] = sh[t] - v;          // exclusive prefix
    if (t == 1023) rowp[N] = sh[1023];        // total
}

// scanC also writes the self-loop entry: col[rowp[i]] = i (slot 0).
__global__ __launch_bounds__(256) void scanC_kernel(
    const int* __restrict__ deg, const int* __restrict__ bpre,
    int* __restrict__ rowp, int* __restrict__ col, int N)
{
    __shared__ int sh[256];
    int b = blockIdx.x, t = threadIdx.x;
    int base = b * SCAN_TILE + t * 4;
    int v[4];
#pragma unroll
    for (int k = 0; k < 4; ++k) {
        int i = base + k;
        v[k] = (i < N) ? deg[i] : 0;
    }
    int tsum = v[0] + v[1] + v[2] + v[3];
    sh[t] = tsum;
    __syncthreads();
    for (int off = 1; off < 256; off <<= 1) {
        int u = (t >= off) ? sh[t - off] : 0;
        __syncthreads();
        sh[t] += u;
        __syncthreads();
    }
    int pre = bpre[b] + sh[t] - tsum;
#pragma unroll
    for (int k = 0; k < 4; ++k) {
        int i = base + k;
        if (i < N) {
            rowp[i] = pre;
            col[pre] = i;   // self loop at slot 0
        }
        pre += v[k];
    }
}

// atomic-free scatter: position fully determined by rowp + recorded slot
__global__ __launch_bounds__(256) void scatter2_kernel(
    const int* __restrict__ src, const int* __restrict__ dst,
    const int* __restrict__ slot, const int* __restrict__ rowp,
    int* __restrict__ col, int E)
{
    int i = blockIdx.x * 256 + threadIdx.x;
    if (i < E) col[rowp[dst[i]] + slot[i]] = src[i];
}

// ---------------------------------------------------------------------------
// Layer-0 rank-1 precompute + layer-2 epilogue constant C = sum(b2*pW)+pb.
// PARALLELIZED: 8 lanes per output j, 16-deep serial dot + 3-step shfl
// reduce (was 128 threads x 128-deep serial dot, latency-bound).
__global__ __launch_bounds__(1024) void rank1_prep_kernel(
    const float* __restrict__ lW, const float* __restrict__ lb,
    const float* __restrict__ W0, const float* __restrict__ al,
    const float* __restrict__ ar, const float* __restrict__ cb2,
    const float* __restrict__ pW, const float* __restrict__ pb,
    float* __restrict__ c1, float* __restrict__ c2, float* __restrict__ prm)
{
    __shared__ float sh1[128], sh2[128], sh3[128], sh4[128], sh5[128];
    int t = threadIdx.x;
    int j = t >> 3, sub = t & 7;     // 8 consecutive lanes per j
    float s1 = 0.f, s2 = 0.f;
    int d0 = sub * 16;
#pragma unroll
    for (int k = 0; k < 16; ++k) {
        float wv = W0[j * 128 + d0 + k];
        s1 += lW[d0 + k] * wv;
        s2 += lb[d0 + k] * wv;
    }
#pragma unroll
    for (int m = 1; m <= 4; m <<= 1) {      // reduce within the 8-lane group
        s1 += __shfl_xor(s1, m, 64);
        s2 += __shfl_xor(s2, m, 64);
    }
    if (sub == 0) {
        c1[j] = s1; c2[j] = s2;
        sh1[j] = s1 * al[j]; sh2[j] = s2 * al[j];
        sh3[j] = s1 * ar[j]; sh4[j] = s2 * ar[j];
        sh5[j] = cb2[j] * pW[j];
    }
    __syncthreads();
    if (t < 4) {
        float p = 0.f, q = 0.f, r = 0.f, s = 0.f;
        for (int f = 0; f < 32; ++f) {
            p += sh1[t * 32 + f]; q += sh2[t * 32 + f];
            r += sh3[t * 32 + f]; s += sh4[t * 32 + f];
        }
        prm[t] = p; prm[4 + t] = q; prm[8 + t] = r; prm[12 + t] = s;
    }
    if (t == 0) {
        float cs = 0.f;
        for (int k = 0; k < 128; ++k) cs += sh5[k];
        prm[16] = cs + pb[0];
    }
}

// ---------------------------------------------------------------------------
// LAYER-0 aggregation via rank-1 identity: h0[u] = w[u]*c1 + c2, so
// sum_u p*h0[u] = (sum p*w_u)*c1 + (sum p)*c2. Per-edge gather is ONLY
// w[u] (4B; 400KB array -> per-XCD-L2-resident) and el0[u] = w_u*pl+ql
// is computed in-register.
__global__ __launch_bounds__(256) void agg0_kernel(
    const float* __restrict__ w, const float* __restrict__ c1,
    const float* __restrict__ c2, const float* __restrict__ prm,
    const int* __restrict__ rowp, const int* __restrict__ col,
    const float* __restrict__ bias, unsigned short* __restrict__ xout, int N)
{
    const int lane = threadIdx.x & 63;
    const int q    = lane >> 4;
    const int l16  = lane & 15;
    const int v    = blockIdx.x * 16 + (threadIdx.x >> 6) * 4 + q;
    if (v >= N) return;

    const int r0 = rowp[v], r1 = rowp[v + 1];
    const int head = l16 >> 2;
    const int f0   = l16 * 8;
    const float pl = prm[head],     ql = prm[4 + head];
    const float pr = prm[8 + head], qr = prm[12 + head];

    const float wv  = w[v];
    const float erq = wv * pr + qr;
    const float mref = leaky02(wv * pl + ql + erq);   // self-loop e

    float S = 0.f, Sw = 0.f;
    float w_cur = wv;                                  // col[r0] == v
    for (int j = r0; j < r1; ++j) {
        int jn = (j + 1 < r1) ? (j + 1) : j;
        float w_nxt = w[col[jn]];

        float e = leaky02(w_cur * pl + ql + erq);
        float d = fminf(e - mref, 80.f);
        float p = __expf(d);
        S += p; Sw += p * w_cur;
        w_cur = w_nxt;
    }
    const float t = Sw / S;

    float4 a0 = *reinterpret_cast<const float4*>(&c1[f0]);
    float4 a1 = *reinterpret_cast<const float4*>(&c1[f0 + 4]);
    float4 g0 = *reinterpret_cast<const float4*>(&c2[f0]);
    float4 g1 = *reinterpret_cast<const float4*>(&c2[f0 + 4]);
    float4 b0 = *reinterpret_cast<const float4*>(&bias[f0]);
    float4 b1 = *reinterpret_cast<const float4*>(&bias[f0 + 4]);
    const float aa[8] = {a0.x, a0.y, a0.z, a0.w, a1.x, a1.y, a1.z, a1.w};
    const float gg[8] = {g0.x, g0.y, g0.z, g0.w, g1.x, g1.y, g1.z, g1.w};
    const float bb[8] = {b0.x, b0.y, b0.z, b0.w, b1.x, b1.y, b1.z, b1.w};

    u16x8 o;
#pragma unroll
    for (int k = 0; k < 8; ++k)
        o[k] = f2bf(leaky01(t * aa[k] + gg[k] + bb[k]));
    *reinterpret_cast<u16x8*>(&xout[(size_t)v * 128 + f0]) = o;
}

// ---------------------------------------------------------------------------
// MFMA bf16 GEMM (layers 1,2) + fused el/er tile — 32 rows/wave,
// FRAGMENT-PACKED W. mode 0 (layer1): write hb + el + er.
// mode 1 (layer2): skip hb; write yel[row*8+h*2] = {y_h = h.pW_h, el_h} + er.
__global__ __launch_bounds__(256) void gemm_mfma_kernel(
    const unsigned short* __restrict__ xb, const short* __restrict__ Wh,
    const short* __restrict__ Wl, const short* __restrict__ Mh,
    const short* __restrict__ Ml, unsigned short* __restrict__ hb,
    float* __restrict__ el, float* __restrict__ er,
    const float* __restrict__ pW, float* __restrict__ yel,
    int N, int mode)
{
    const int lane = threadIdx.x & 63;
    const int wv   = threadIdx.x >> 6;
    const int m0   = blockIdx.x * 128 + wv * 32;  // 32 rows per wave
    const int mr   = lane & 15;
    const int quad = lane >> 4;

    int r0 = m0 + mr;      if (r0 > N - 1) r0 = N - 1;   // clamped load rows
    int r1 = m0 + 16 + mr; if (r1 > N - 1) r1 = N - 1;
    const unsigned short* xp0 = xb + (size_t)r0 * 128 + quad * 8;
    const unsigned short* xp1 = xb + (size_t)r1 * 128 + quad * 8;

    f32x4 acc0[8], acc1[8], acce0, acce1;
#pragma unroll
    for (int c = 0; c < 8; ++c) {
        acc0[c] = (f32x4){0.f, 0.f, 0.f, 0.f};
        acc1[c] = (f32x4){0.f, 0.f, 0.f, 0.f};
    }
    acce0 = (f32x4){0.f, 0.f, 0.f, 0.f};
    acce1 = (f32x4){0.f, 0.f, 0.f, 0.f};

#pragma unroll
    for (int kk = 0; kk < 4; ++kk) {
        bf16x8 a0 = *reinterpret_cast<const bf16x8*>(xp0 + kk * 32);
        bf16x8 a1 = *reinterpret_cast<const bf16x8*>(xp1 + kk * 32);

        const int kb = kk * 32 + quad * 8;
        bf16x8 bh[8], bl[8];
#pragma unroll
        for (int c = 0; c < 8; ++c) {
            const size_t wo = (size_t)((kk * 8 + c) * 64 + lane) * 8;
            bh[c] = *reinterpret_cast<const bf16x8*>(Wh + wo);
            bl[c] = *reinterpret_cast<const bf16x8*>(Wl + wo);
        }
        bf16x8 eh = *reinterpret_cast<const bf16x8*>(Mh + (size_t)mr * 128 + kb);
        bf16x8 eo = *reinterpret_cast<const bf16x8*>(Ml + (size_t)mr * 128 + kb);
#pragma unroll
        for (int c = 0; c < 8; ++c) {
            acc0[c] = __builtin_amdgcn_mfma_f32_16x16x32_bf16(a0, bh[c], acc0[c], 0, 0, 0);
            acc0[c] = __builtin_amdgcn_mfma_f32_16x16x32_bf16(a0, bl[c], acc0[c], 0, 0, 0);
            acc1[c] = __builtin_amdgcn_mfma_f32_16x16x32_bf16(a1, bh[c], acc1[c], 0, 0, 0);
            acc1[c] = __builtin_amdgcn_mfma_f32_16x16x32_bf16(a1, bl[c], acc1[c], 0, 0, 0);
        }
        acce0 = __builtin_amdgcn_mfma_f32_16x16x32_bf16(a0, eh, acce0, 0, 0, 0);
        acce0 = __builtin_amdgcn_mfma_f32_16x16x32_bf16(a0, eo, acce0, 0, 0, 0);
        acce1 = __builtin_amdgcn_mfma_f32_16x16x32_bf16(a1, eh, acce1, 0, 0, 0);
        acce1 = __builtin_amdgcn_mfma_f32_16x16x32_bf16(a1, eo, acce1, 0, 0, 0);
    }

    if (mode == 0) {
#pragma unroll
        for (int i = 0; i < 4; ++i) {
            int rowA = m0 + quad * 4 + i;
            if (rowA < N) {
                unsigned short* hp = hb + (size_t)rowA * 128 + mr;
#pragma unroll
                for (int c = 0; c < 8; ++c) hp[c * 16] = f2bf(acc0[c][i]);
                if (mr < 4)       el[(size_t)rowA * 4 + mr]       = acce0[i];
                else if (mr < 8)  er[(size_t)rowA * 4 + (mr - 4)] = acce0[i];
            }
            int rowB = m0 + 16 + quad * 4 + i;
            if (rowB < N) {
                unsigned short* hp = hb + (size_t)rowB * 128 + mr;
#pragma unroll
                for (int c = 0; c < 8; ++c) hp[c * 16] = f2bf(acc1[c][i]);
                if (mr < 4)       el[(size_t)rowB * 4 + mr]       = acce1[i];
                else if (mr < 8)  er[(size_t)rowB * 4 + (mr - 4)] = acce1[i];
            }
        }
    } else {
        // y_h = sum_f h[row, 32h..32h+31] * pW[...]; feature f = mr + c*16
        float pw[8];
#pragma unroll
        for (int c = 0; c < 8; ++c) pw[c] = pW[mr + c * 16];
#pragma unroll
        for (int i = 0; i < 4; ++i) {
            int rowA = m0 + quad * 4 + i;
            {
                float y[4];
#pragma unroll
                for (int h = 0; h < 4; ++h)
                    y[h] = acc0[2 * h][i] * pw[2 * h] + acc0[2 * h + 1][i] * pw[2 * h + 1];
#pragma unroll
                for (int d = 1; d < 16; d <<= 1) {
#pragma unroll
                    for (int h = 0; h < 4; ++h) y[h] += __shfl_xor(y[h], d, 64);
                }
                if (rowA < N) {
                    if (mr < 4) {
                        float2 o; o.x = y[mr]; o.y = acce0[i];
                        *reinterpret_cast<float2*>(&yel[(size_t)rowA * 8 + mr * 2]) = o;
                    } else if (mr < 8) {
                        er[(size_t)rowA * 4 + (mr - 4)] = acce0[i];
                    }
                }
            }
            int rowB = m0 + 16 + quad * 4 + i;
            {
                float y[4];
#pragma unroll
                for (int h = 0; h < 4; ++h)
                    y[h] = acc1[2 * h][i] * pw[2 * h] + acc1[2 * h + 1][i] * pw[2 * h + 1];
#pragma unroll
                for (int d = 1; d < 16; d <<= 1) {
#pragma unroll
                    for (int h = 0; h < 4; ++h) y[h] += __shfl_xor(y[h], d, 64);
                }
                if (rowB < N) {
                    if (mr < 4) {
                        float2 o; o.x = y[mr]; o.y = acce1[i];
                        *reinterpret_cast<float2*>(&yel[(size_t)rowB * 8 + mr * 2]) = o;
                    } else if (mr < 8) {
                        er[(size_t)rowB * 4 + (mr - 4)] = acce1[i];
                    }
                }
            }
        }
    }
}

// ---------------------------------------------------------------------------
// MIDDLE-layer aggregation (full 256B h-row gather — irreducible) with
// fixed-reference defer-max, branchless clamp.
__global__ __launch_bounds__(256) void agg_mid_kernel(
    const unsigned short* __restrict__ hb, const float* __restrict__ el,
    const float* __restrict__ er, const int* __restrict__ rowp,
    const int* __restrict__ col, const float* __restrict__ bias,
    unsigned short* __restrict__ xout, int N)
{
    const int lane = threadIdx.x & 63;
    const int q    = lane >> 4;
    const int l16  = lane & 15;
    const int v    = blockIdx.x * 16 + (threadIdx.x >> 6) * 4 + q;
    if (v >= N) return;

    const int r0 = rowp[v], r1 = rowp[v + 1];
    const int head = l16 >> 2;
    const int f0   = l16 * 8;
    const float erq = er[(size_t)v * 4 + head];
    const float el_self = el[(size_t)v * 4 + head];
    const float mref = leaky02(el_self + erq);

    float s = 0.f;
    float acc[8];
#pragma unroll
    for (int k = 0; k < 8; ++k) acc[k] = 0.f;

    float el_cur = el_self;                    // col[r0] == v
    u16x8 hv_cur = *reinterpret_cast<const u16x8*>(&hb[(size_t)v * 128 + f0]);

    for (int j = r0; j < r1; ++j) {
        int jn = (j + 1 < r1) ? (j + 1) : j;
        int   u_nxt  = col[jn];
        float el_nxt = el[(size_t)u_nxt * 4 + head];
        u16x8 hv_nxt = *reinterpret_cast<const u16x8*>(&hb[(size_t)u_nxt * 128 + f0]);

        float e = leaky02(el_cur + erq);
        float d = fminf(e - mref, 80.f);
        float p = __expf(d);
        s += p;
#pragma unroll
        for (int k = 0; k < 8; ++k) acc[k] += p * bf2f(hv_cur[k]);

        el_cur = el_nxt; hv_cur = hv_nxt;
    }
    const float is = 1.f / s;

    float4 b0 = *reinterpret_cast<const float4*>(&bias[f0]);
    float4 b1 = *reinterpret_cast<const float4*>(&bias[f0 + 4]);
    const float bb[8] = {b0.x, b0.y, b0.z, b0.w, b1.x, b1.y, b1.z, b1.w};

    u16x8 o;
#pragma unroll
    for (int k = 0; k < 8; ++k) o[k] = f2bf(leaky01(acc[k] * is + bb[k]));
    *reinterpret_cast<u16x8*>(&xout[(size_t)v * 128 + f0]) = o;
}

// ---------------------------------------------------------------------------
// LAST-layer aggregation: logits[v] = sum_h (sum_u p*y_uh)/S_h + C.
// Gathers only yel {y,el} float2 per (u,head) — 3.2MB array, L2-resident.
__global__ __launch_bounds__(256) void agg2_kernel(
    const float* __restrict__ yel, const float* __restrict__ er,
    const int* __restrict__ rowp, const int* __restrict__ col,
    const float* __restrict__ prm, float* __restrict__ logits, int N)
{
    const int lane = threadIdx.x & 63;
    const int q    = lane >> 4;
    const int l16  = lane & 15;
    const int v    = blockIdx.x * 16 + (threadIdx.x >> 6) * 4 + q;
    if (v >= N) return;

    const int r0 = rowp[v], r1 = rowp[v + 1];
    const int head = l16 >> 2;
    const float erq = er[(size_t)v * 4 + head];

    float2 cur = *reinterpret_cast<const float2*>(&yel[(size_t)v * 8 + head * 2]);
    const float mref = leaky02(cur.y + erq);   // self-loop e (col[r0]==v)

    float S = 0.f, A = 0.f;
    for (int j = r0; j < r1; ++j) {
        int jn = (j + 1 < r1) ? (j + 1) : j;
        int u = col[jn];
        float2 nxt = *reinterpret_cast<const float2*>(&yel[(size_t)u * 8 + head * 2]);

        float e = leaky02(cur.y + erq);
        float d = fminf(e - mref, 80.f);
        float p = __expf(d);
        S += p; A += p * cur.x;
        cur = nxt;
    }
    float part = A / S;
    part += __shfl_xor(part, 4, 64);
    part += __shfl_xor(part, 8, 64);
    if (l16 == 0) logits[v] = part + prm[16];
}

// ---------------------------------------------------------------------------
extern "C" void kernel_launch(void* const* d_in, const int* in_sizes, int n_in,
                              void* d_out, int out_size, void* d_ws, size_t ws_size,
                              hipStream_t stream)
{
    const float* weights = (const float*)d_in[0];
    const float* lin_W   = (const float*)d_in[1];
    const float* lin_b   = (const float*)d_in[2];
    const float* fc_W    = (const float*)d_in[3];
    const float* attn_l  = (const float*)d_in[4];
    const float* attn_r  = (const float*)d_in[5];
    const float* conv_b  = (const float*)d_in[6];
    const float* pred_W  = (const float*)d_in[7];
    const float* pred_b  = (const float*)d_in[8];
    const int*   src     = (const int*)d_in[9];
    const int*   dst     = (const int*)d_in[10];

    const int N = in_sizes[0];
    const int E = in_sizes[9];
    const int NB = (N + SCAN_TILE - 1) / SCAN_TILE;

    // workspace layout (16B-aligned sections)
    unsigned short* xb = (unsigned short*)d_ws;                    // N*128 bf16 (pre-activated)
    unsigned short* hb = xb + (size_t)N * 128;                     // N*128 bf16
    float* el  = (float*)(hb + (size_t)N * 128);                   // N*4
    float* er  = el + (size_t)N * 4;                               // N*4
    float* yel = er + (size_t)N * 4;                               // N*8 {y,el} per head
    float* c1  = yel + (size_t)N * 8;                              // 128
    float* c2  = c1 + 128;                                         // 128
    float* prm = c2 + 128;                                         // 32
    short* Whs = (short*)(prm + 32);                               // 2*16384 bf16 (packed)
    short* Wls = Whs + 2 * 16384;                                  // 2*16384 bf16 (packed)
    short* Mhs = Wls + 2 * 16384;                                  // 2*2048 bf16 (Mext hi)
    short* Mls = Mhs + 2 * 2048;                                   // 2*2048 bf16 (Mext lo)
    int*   deg  = (int*)(Mls + 2 * 2048);                          // N
    int*   rowp = deg + N;                                         // N+1
    int*   slot = rowp + (N + 1);                                  // E
    int*   col  = slot + E;                                        // E+N
    int*   bsum = col + (E + N);                                   // NB
    int*   bpre = bsum + NB;                                       // NB

    // CSR build + packed W split (fresh every call: ws is re-poisoned)
    init_split_kernel<<<(N + 255) / 256, 256, 0, stream>>>(
        deg, N, fc_W + 16384, Whs, Wls, 2 * 16384);
    mlr_prep_kernel<<<2, 1024, 0, stream>>>(fc_W, attn_l, attn_r, Mhs, Mls);
    deg_count_slot_kernel<<<(E + 255) / 256, 256, 0, stream>>>(dst, deg, slot, E);
    scanA_kernel<<<NB, 256, 0, stream>>>(deg, bsum, N);
    scanB_kernel<<<1, 1024, 0, stream>>>(bsum, bpre, rowp, NB, N);
    scanC_kernel<<<NB, 256, 0, stream>>>(deg, bpre, rowp, col, N);
    scatter2_kernel<<<(E + 255) / 256, 256, 0, stream>>>(src, dst, slot, rowp, col, E);

    rank1_prep_kernel<<<1, 1024, 0, stream>>>(
        lin_W, lin_b, fc_W, attn_l, attn_r, conv_b + 2 * 128, pred_W, pred_b,
        c1, c2, prm);

    // Layer 0: rank-1 aggregation straight from w (no h0 materialization)
    agg0_kernel<<<(N + 15) / 16, 256, 0, stream>>>(
        weights, c1, c2, prm, rowp, col, conv_b, xb, N);

    // Layer 1: gemm (mode 0) + full-gather aggregation
    gemm_mfma_kernel<<<(N + 127) / 128, 256, 0, stream>>>(
        xb, Whs, Wls, Mhs, Mls, hb, el, er, pred_W, yel, N, 0);
    agg_mid_kernel<<<(N + 15) / 16, 256, 0, stream>>>(
        hb, el, er, rowp, col, conv_b + 128, xb, N);

    // Layer 2: gemm (mode 1: y=h.pW + el packed) + light aggregation
    gemm_mfma_kernel<<<(N + 127) / 128, 256, 0, stream>>>(
        xb, Whs + 16384, Wls + 16384, Mhs + 2048, Mls + 2048,
        hb, el, er, pred_W, yel, N, 1);
    agg2_kernel<<<(N + 15) / 16, 256, 0, stream>>>(
        yel, er, rowp, col, prm, (float*)d_out, N);
}

// Round 5
// 274.559 us; speedup vs baseline: 1.3705x; 1.0015x over previous
//
#include <hip/hip_runtime.h>
#include <hip/hip_bf16.h>
#include <math.h>

// Problem constants: N=100000, E=600000, D=128, H=4, F=32, L=3

__device__ __forceinline__ float leaky02(float x) {
    return x >= 0.f ? x : 0.2f * x;
}
__device__ __forceinline__ float leaky01(float x) {
    return x >= 0.f ? x : 0.01f * x;
}

// bf16 helpers (round-to-nearest-even)
__device__ __forceinline__ unsigned short f2bf(float f) {
    unsigned u = __float_as_uint(f);
    unsigned r = u + 0x7FFFu + ((u >> 16) & 1u);
    return (unsigned short)(r >> 16);
}
__device__ __forceinline__ float bf2f(unsigned short s) {
    return __uint_as_float(((unsigned)s) << 16);
}

typedef __attribute__((ext_vector_type(8))) short bf16x8;
typedef __attribute__((ext_vector_type(8))) unsigned short u16x8;
typedef __attribute__((ext_vector_type(4))) float f32x4;

// ---------------------------------------------------------------------------
// Fused init: deg[i]=1 + W split into bf16 hi/lo, PACKED IN FRAGMENT ORDER.
__global__ __launch_bounds__(256) void init_split_kernel(
    int* __restrict__ deg, int N, const float* __restrict__ W,
    short* __restrict__ Wh, short* __restrict__ Wl, int n)
{
    int i = blockIdx.x * 256 + threadIdx.x;
    if (i < N) deg[i] = 1;
    if (i < n) {
        int l    = i >> 14;          // layer (0,1)
        int p    = i & 16383;
        int j    = p & 7;
        int lane = (p >> 3) & 63;
        int c    = (p >> 9) & 7;
        int kk   = p >> 12;
        int mr   = lane & 15;
        int quad = lane >> 4;
        int row  = c * 16 + mr;
        int d    = kk * 32 + quad * 8 + j;
        float f = W[(size_t)l * 16384 + row * 128 + d];
        unsigned short hi = f2bf(f);
        Wh[i] = (short)hi;
        Wl[i] = (short)f2bf(f - bf2f(hi));
    }
}

// Mext[r][d] per layer — PARALLELIZED: one thread per (r,d) output element.
__global__ __launch_bounds__(1024) void mlr_prep_kernel(
    const float* __restrict__ fc_W, const float* __restrict__ attn_l,
    const float* __restrict__ attn_r, short* __restrict__ Mh,
    short* __restrict__ Ml)
{
    int l = blockIdx.x;                       // 0,1 -> layers 1,2
    const float* W  = fc_W + (size_t)(l + 1) * 16384;
    const float* al = attn_l + (l + 1) * 128;
    const float* ar = attn_r + (l + 1) * 128;
    short* mh = Mh + (size_t)l * 16 * 128;
    short* ml = Ml + (size_t)l * 16 * 128;
    int t = threadIdx.x;
    int r = t >> 7;                           // 0..7
    int d = t & 127;
    int hh = r & 3;
    const float* av = (r < 4) ? al : ar;
    float s = 0.f;
#pragma unroll
    for (int f = 0; f < 32; ++f)
        s += W[(size_t)(hh * 32 + f) * 128 + d] * av[hh * 32 + f];
    unsigned short hi = f2bf(s);
    mh[r * 128 + d] = (short)hi;
    ml[r * 128 + d] = (short)f2bf(s - bf2f(hi));
    mh[(r + 8) * 128 + d] = 0;                // zero rows 8..15
    ml[(r + 8) * 128 + d] = 0;
}

// slot[i] = old count (>=1 because self loop holds slot 0)
__global__ __launch_bounds__(256) void deg_count_slot_kernel(
    const int* __restrict__ dst, int* __restrict__ deg,
    int* __restrict__ slot, int E)
{
    int i = blockIdx.x * 256 + threadIdx.x;
    if (i < E) slot[i] = atomicAdd(&deg[dst[i]], 1);
}

#define SCAN_TILE 1024

__global__ __launch_bounds__(256) void scanA_kernel(
    const int* __restrict__ deg, int* __restrict__ bsum, int N)
{
    __shared__ int ws[4];
    int b = blockIdx.x, t = threadIdx.x;
    int base = b * SCAN_TILE + t * 4;
    int s = 0;
#pragma unroll
    for (int k = 0; k < 4; ++k) {
        int i = base + k;
        if (i < N) s += deg[i];
    }
#pragma unroll
    for (int m = 32; m >= 1; m >>= 1) s += __shfl_xor(s, m, 64);
    if ((t & 63) == 0) ws[t >> 6] = s;
    __syncthreads();
    if (t == 0) bsum[b] = ws[0] + ws[1] + ws[2] + ws[3];
}

__global__ __launch_bounds__(1024) void scanB_kernel(
    int* __restrict__ bsum, int* __restrict__ bpre, int* __restrict__ rowp,
    int NB, int N)
{
    __shared__ int sh[1024];
    int t = threadIdx.x;
    int v = (t < NB) ? bsum[t] : 0;
    sh[t] = v;
    __syncthreads();
    for (int off = 1; off < 1024; off <<= 1) {
        int u = (t >= off) ? sh[t - off] : 0;
        __syncthreads();
        sh[t] += u;
        __syncthreads();
    }
    if (t < NB) bpre[t] = sh[t] - v;          // exclusive prefix
    if (t == 1023) rowp[N] = sh[1023];        // total
}

// scanC also writes the self-loop entry: col[rowp[i]] = i (slot 0).
__global__ __launch_bounds__(256) void scanC_kernel(
    const int* __restrict__ deg, const int* __restrict__ bpre,
    int* __restrict__ rowp, int* __restrict__ col, int N)
{
    __shared__ int sh[256];
    int b = blockIdx.x, t = threadIdx.x;
    int base = b * SCAN_TILE + t * 4;
    int v[4];
#pragma unroll
    for (int k = 0; k < 4; ++k) {
        int i = base + k;
        v[k] = (i < N) ? deg[i] : 0;
    }
    int tsum = v[0] + v[1] + v[2] + v[3];
    sh[t] = tsum;
    __syncthreads();
    for (int off = 1; off < 256; off <<= 1) {
        int u = (t >= off) ? sh[t - off] : 0;
        __syncthreads();
        sh[t] += u;
        __syncthreads();
    }
    int pre = bpre[b] + sh[t] - tsum;
#pragma unroll
    for (int k = 0; k < 4; ++k) {
        int i = base + k;
        if (i < N) {
            rowp[i] = pre;
            col[pre] = i;   // self loop at slot 0
        }
        pre += v[k];
    }
}

// atomic-free scatter: position fully determined by rowp + recorded slot
__global__ __launch_bounds__(256) void scatter2_kernel(
    const int* __restrict__ src, const int* __restrict__ dst,
    const int* __restrict__ slot, const int* __restrict__ rowp,
    int* __restrict__ col, int E)
{
    int i = blockIdx.x * 256 + threadIdx.x;
    if (i < E) col[rowp[dst[i]] + slot[i]] = src[i];
}

// ---------------------------------------------------------------------------
// Layer-0 rank-1 precompute + layer-2 epilogue constant C = sum(b2*pW)+pb.
__global__ __launch_bounds__(1024) void rank1_prep_kernel(
    const float* __restrict__ lW, const float* __restrict__ lb,
    const float* __restrict__ W0, const float* __restrict__ al,
    const float* __restrict__ ar, const float* __restrict__ cb2,
    const float* __restrict__ pW, const float* __restrict__ pb,
    float* __restrict__ c1, float* __restrict__ c2, float* __restrict__ prm)
{
    __shared__ float sh1[128], sh2[128], sh3[128], sh4[128], sh5[128];
    int t = threadIdx.x;
    int j = t >> 3, sub = t & 7;     // 8 consecutive lanes per j
    float s1 = 0.f, s2 = 0.f;
    int d0 = sub * 16;
#pragma unroll
    for (int k = 0; k < 16; ++k) {
        float wv = W0[j * 128 + d0 + k];
        s1 += lW[d0 + k] * wv;
        s2 += lb[d0 + k] * wv;
    }
#pragma unroll
    for (int m = 1; m <= 4; m <<= 1) {      // reduce within the 8-lane group
        s1 += __shfl_xor(s1, m, 64);
        s2 += __shfl_xor(s2, m, 64);
    }
    if (sub == 0) {
        c1[j] = s1; c2[j] = s2;
        sh1[j] = s1 * al[j]; sh2[j] = s2 * al[j];
        sh3[j] = s1 * ar[j]; sh4[j] = s2 * ar[j];
        sh5[j] = cb2[j] * pW[j];
    }
    __syncthreads();
    if (t < 4) {
        float p = 0.f, q = 0.f, r = 0.f, s = 0.f;
        for (int f = 0; f < 32; ++f) {
            p += sh1[t * 32 + f]; q += sh2[t * 32 + f];
            r += sh3[t * 32 + f]; s += sh4[t * 32 + f];
        }
        prm[t] = p; prm[4 + t] = q; prm[8 + t] = r; prm[12 + t] = s;
    }
    if (t == 0) {
        float cs = 0.f;
        for (int k = 0; k < 128; ++k) cs += sh5[k];
        prm[16] = cs + pb[0];
    }
}

// ---------------------------------------------------------------------------
// LAYER-0 aggregation via rank-1 identity (4B w-gathers, L2-resident).
__global__ __launch_bounds__(256) void agg0_kernel(
    const float* __restrict__ w, const float* __restrict__ c1,
    const float* __restrict__ c2, const float* __restrict__ prm,
    const int* __restrict__ rowp, const int* __restrict__ col,
    const float* __restrict__ bias, unsigned short* __restrict__ xout, int N)
{
    const int lane = threadIdx.x & 63;
    const int q    = lane >> 4;
    const int l16  = lane & 15;
    const int v    = blockIdx.x * 16 + (threadIdx.x >> 6) * 4 + q;
    if (v >= N) return;

    const int r0 = rowp[v], r1 = rowp[v + 1];
    const int head = l16 >> 2;
    const int f0   = l16 * 8;
    const float pl = prm[head],     ql = prm[4 + head];
    const float pr = prm[8 + head], qr = prm[12 + head];

    const float wv  = w[v];
    const float erq = wv * pr + qr;
    const float mref = leaky02(wv * pl + ql + erq);   // self-loop e

    float S = 0.f, Sw = 0.f;
    float w_cur = wv;                                  // col[r0] == v
    for (int j = r0; j < r1; ++j) {
        int jn = (j + 1 < r1) ? (j + 1) : j;
        float w_nxt = w[col[jn]];

        float e = leaky02(w_cur * pl + ql + erq);
        float d = fminf(e - mref, 80.f);
        float p = __expf(d);
        S += p; Sw += p * w_cur;
        w_cur = w_nxt;
    }
    const float t = Sw / S;

    float4 a0 = *reinterpret_cast<const float4*>(&c1[f0]);
    float4 a1 = *reinterpret_cast<const float4*>(&c1[f0 + 4]);
    float4 g0 = *reinterpret_cast<const float4*>(&c2[f0]);
    float4 g1 = *reinterpret_cast<const float4*>(&c2[f0 + 4]);
    float4 b0 = *reinterpret_cast<const float4*>(&bias[f0]);
    float4 b1 = *reinterpret_cast<const float4*>(&bias[f0 + 4]);
    const float aa[8] = {a0.x, a0.y, a0.z, a0.w, a1.x, a1.y, a1.z, a1.w};
    const float gg[8] = {g0.x, g0.y, g0.z, g0.w, g1.x, g1.y, g1.z, g1.w};
    const float bb[8] = {b0.x, b0.y, b0.z, b0.w, b1.x, b1.y, b1.z, b1.w};

    u16x8 o;
#pragma unroll
    for (int k = 0; k < 8; ++k)
        o[k] = f2bf(leaky01(t * aa[k] + gg[k] + bb[k]));
    *reinterpret_cast<u16x8*>(&xout[(size_t)v * 128 + f0]) = o;
}

// ---------------------------------------------------------------------------
// MFMA bf16 GEMM (layers 1,2) + fused el/er tile — 32 rows/wave,
// FRAGMENT-PACKED W. mode 0 (layer1): write hb + el + er.
// mode 1 (layer2): skip hb; write yel[row*8+h*2] = {y_h = h.pW_h, el_h} + er.
__global__ __launch_bounds__(256) void gemm_mfma_kernel(
    const unsigned short* __restrict__ xb, const short* __restrict__ Wh,
    const short* __restrict__ Wl, const short* __restrict__ Mh,
    const short* __restrict__ Ml, unsigned short* __restrict__ hb,
    float* __restrict__ el, float* __restrict__ er,
    const float* __restrict__ pW, float* __restrict__ yel,
    int N, int mode)
{
    const int lane = threadIdx.x & 63;
    const int wv   = threadIdx.x >> 6;
    const int m0   = blockIdx.x * 128 + wv * 32;  // 32 rows per wave
    const int mr   = lane & 15;
    const int quad = lane >> 4;

    int r0 = m0 + mr;      if (r0 > N - 1) r0 = N - 1;   // clamped load rows
    int r1 = m0 + 16 + mr; if (r1 > N - 1) r1 = N - 1;
    const unsigned short* xp0 = xb + (size_t)r0 * 128 + quad * 8;
    const unsigned short* xp1 = xb + (size_t)r1 * 128 + quad * 8;

    f32x4 acc0[8], acc1[8], acce0, acce1;
#pragma unroll
    for (int c = 0; c < 8; ++c) {
        acc0[c] = (f32x4){0.f, 0.f, 0.f, 0.f};
        acc1[c] = (f32x4){0.f, 0.f, 0.f, 0.f};
    }
    acce0 = (f32x4){0.f, 0.f, 0.f, 0.f};
    acce1 = (f32x4){0.f, 0.f, 0.f, 0.f};

#pragma unroll
    for (int kk = 0; kk < 4; ++kk) {
        bf16x8 a0 = *reinterpret_cast<const bf16x8*>(xp0 + kk * 32);
        bf16x8 a1 = *reinterpret_cast<const bf16x8*>(xp1 + kk * 32);

        const int kb = kk * 32 + quad * 8;
        bf16x8 bh[8], bl[8];
#pragma unroll
        for (int c = 0; c < 8; ++c) {
            const size_t wo = (size_t)((kk * 8 + c) * 64 + lane) * 8;
            bh[c] = *reinterpret_cast<const bf16x8*>(Wh + wo);
            bl[c] = *reinterpret_cast<const bf16x8*>(Wl + wo);
        }
        bf16x8 eh = *reinterpret_cast<const bf16x8*>(Mh + (size_t)mr * 128 + kb);
        bf16x8 eo = *reinterpret_cast<const bf16x8*>(Ml + (size_t)mr * 128 + kb);
#pragma unroll
        for (int c = 0; c < 8; ++c) {
            acc0[c] = __builtin_amdgcn_mfma_f32_16x16x32_bf16(a0, bh[c], acc0[c], 0, 0, 0);
            acc0[c] = __builtin_amdgcn_mfma_f32_16x16x32_bf16(a0, bl[c], acc0[c], 0, 0, 0);
            acc1[c] = __builtin_amdgcn_mfma_f32_16x16x32_bf16(a1, bh[c], acc1[c], 0, 0, 0);
            acc1[c] = __builtin_amdgcn_mfma_f32_16x16x32_bf16(a1, bl[c], acc1[c], 0, 0, 0);
        }
        acce0 = __builtin_amdgcn_mfma_f32_16x16x32_bf16(a0, eh, acce0, 0, 0, 0);
        acce0 = __builtin_amdgcn_mfma_f32_16x16x32_bf16(a0, eo, acce0, 0, 0, 0);
        acce1 = __builtin_amdgcn_mfma_f32_16x16x32_bf16(a1, eh, acce1, 0, 0, 0);
        acce1 = __builtin_amdgcn_mfma_f32_16x16x32_bf16(a1, eo, acce1, 0, 0, 0);
    }

    if (mode == 0) {
#pragma unroll
        for (int i = 0; i < 4; ++i) {
            int rowA = m0 + quad * 4 + i;
            if (rowA < N) {
                unsigned short* hp = hb + (size_t)rowA * 128 + mr;
#pragma unroll
                for (int c = 0; c < 8; ++c) hp[c * 16] = f2bf(acc0[c][i]);
                if (mr < 4)       el[(size_t)rowA * 4 + mr]       = acce0[i];
                else if (mr < 8)  er[(size_t)rowA * 4 + (mr - 4)] = acce0[i];
            }
            int rowB = m0 + 16 + quad * 4 + i;
            if (rowB < N) {
                unsigned short* hp = hb + (size_t)rowB * 128 + mr;
#pragma unroll
                for (int c = 0; c < 8; ++c) hp[c * 16] = f2bf(acc1[c][i]);
                if (mr < 4)       el[(size_t)rowB * 4 + mr]       = acce1[i];
                else if (mr < 8)  er[(size_t)rowB * 4 + (mr - 4)] = acce1[i];
            }
        }
    } else {
        // y_h = sum_f h[row, 32h..32h+31] * pW[...]; feature f = mr + c*16
        float pw[8];
#pragma unroll
        for (int c = 0; c < 8; ++c) pw[c] = pW[mr + c * 16];
#pragma unroll
        for (int i = 0; i < 4; ++i) {
            int rowA = m0 + quad * 4 + i;
            {
                float y[4];
#pragma unroll
                for (int h = 0; h < 4; ++h)
                    y[h] = acc0[2 * h][i] * pw[2 * h] + acc0[2 * h + 1][i] * pw[2 * h + 1];
#pragma unroll
                for (int d = 1; d < 16; d <<= 1) {
#pragma unroll
                    for (int h = 0; h < 4; ++h) y[h] += __shfl_xor(y[h], d, 64);
                }
                if (rowA < N) {
                    if (mr < 4) {
                        float2 o; o.x = y[mr]; o.y = acce0[i];
                        *reinterpret_cast<float2*>(&yel[(size_t)rowA * 8 + mr * 2]) = o;
                    } else if (mr < 8) {
                        er[(size_t)rowA * 4 + (mr - 4)] = acce0[i];
                    }
                }
            }
            int rowB = m0 + 16 + quad * 4 + i;
            {
                float y[4];
#pragma unroll
                for (int h = 0; h < 4; ++h)
                    y[h] = acc1[2 * h][i] * pw[2 * h] + acc1[2 * h + 1][i] * pw[2 * h + 1];
#pragma unroll
                for (int d = 1; d < 16; d <<= 1) {
#pragma unroll
                    for (int h = 0; h < 4; ++h) y[h] += __shfl_xor(y[h], d, 64);
                }
                if (rowB < N) {
                    if (mr < 4) {
                        float2 o; o.x = y[mr]; o.y = acce1[i];
                        *reinterpret_cast<float2*>(&yel[(size_t)rowB * 8 + mr * 2]) = o;
                    } else if (mr < 8) {
                        er[(size_t)rowB * 4 + (mr - 4)] = acce1[i];
                    }
                }
            }
        }
    }
}

// ---------------------------------------------------------------------------
// MIDDLE-layer aggregation — DEPTH-2 two-stream pipeline. Even edges in
// stream A, odd in stream B, each with its own registers; every h-row
// gather is issued 2 edges before its compute, doubling in-flight bytes
// per wave (Little's law: depth-1 was ~1KB/wave, right at the concurrency
// floor for ~2.4TB/s — depth-2 targets ~2KB/wave).
__global__ __launch_bounds__(256) void agg_mid_kernel(
    const unsigned short* __restrict__ hb, const float* __restrict__ el,
    const float* __restrict__ er, const int* __restrict__ rowp,
    const int* __restrict__ col, const float* __restrict__ bias,
    unsigned short* __restrict__ xout, int N)
{
    const int lane = threadIdx.x & 63;
    const int q    = lane >> 4;
    const int l16  = lane & 15;
    const int v    = blockIdx.x * 16 + (threadIdx.x >> 6) * 4 + q;
    if (v >= N) return;

    const int r0 = rowp[v], r1 = rowp[v + 1];
    const int head = l16 >> 2;
    const int f0   = l16 * 8;
    const float erq = er[(size_t)v * 4 + head];
    const float el_self = el[(size_t)v * 4 + head];
    const float mref = leaky02(el_self + erq);

    float s = 0.f;
    float acc[8];
#pragma unroll
    for (int k = 0; k < 8; ++k) acc[k] = 0.f;

    // prologue: A holds edge r0 (self loop, col[r0]==v), B holds edge r0+1
    float elA = el_self;
    u16x8 hvA = *reinterpret_cast<const u16x8*>(&hb[(size_t)v * 128 + f0]);
    int jB = (r0 + 1 < r1) ? r0 + 1 : r1 - 1;
    int uB = col[jB];
    float elB = el[(size_t)uB * 4 + head];
    u16x8 hvB = *reinterpret_cast<const u16x8*>(&hb[(size_t)uB * 128 + f0]);

    for (int j = r0; j < r1; j += 2) {
        // prefetch A-stream edge j+2 (clamped to a valid edge)
        int jA2 = (j + 2 < r1) ? j + 2 : r1 - 1;
        int uA2 = col[jA2];
        float elA2 = el[(size_t)uA2 * 4 + head];
        u16x8 hvA2 = *reinterpret_cast<const u16x8*>(&hb[(size_t)uA2 * 128 + f0]);

        // compute edge j from A state (its load was issued 2 edges ago)
        {
            float e = leaky02(elA + erq);
            float d = fminf(e - mref, 80.f);
            float p = __expf(d);
            s += p;
#pragma unroll
            for (int k = 0; k < 8; ++k) acc[k] += p * bf2f(hvA[k]);
        }

        if (j + 1 < r1) {
            // prefetch B-stream edge j+3
            int jB2 = (j + 3 < r1) ? j + 3 : r1 - 1;
            int uB2 = col[jB2];
            float elB2 = el[(size_t)uB2 * 4 + head];
            u16x8 hvB2 = *reinterpret_cast<const u16x8*>(&hb[(size_t)uB2 * 128 + f0]);

            // compute edge j+1 from B state
            float e = leaky02(elB + erq);
            float d = fminf(e - mref, 80.f);
            float p = __expf(d);
            s += p;
#pragma unroll
            for (int k = 0; k < 8; ++k) acc[k] += p * bf2f(hvB[k]);

            elB = elB2; hvB = hvB2;
        }
        elA = elA2; hvA = hvA2;
    }
    const float is = 1.f / s;

    float4 b0 = *reinterpret_cast<const float4*>(&bias[f0]);
    float4 b1 = *reinterpret_cast<const float4*>(&bias[f0 + 4]);
    const float bb[8] = {b0.x, b0.y, b0.z, b0.w, b1.x, b1.y, b1.z, b1.w};

    u16x8 o;
#pragma unroll
    for (int k = 0; k < 8; ++k) o[k] = f2bf(leaky01(acc[k] * is + bb[k]));
    *reinterpret_cast<u16x8*>(&xout[(size_t)v * 128 + f0]) = o;
}

// ---------------------------------------------------------------------------
// LAST-layer aggregation — same depth-2 two-stream pipeline on the 8B
// yel gathers (3.2MB array).
__global__ __launch_bounds__(256) void agg2_kernel(
    const float* __restrict__ yel, const float* __restrict__ er,
    const int* __restrict__ rowp, const int* __restrict__ col,
    const float* __restrict__ prm, float* __restrict__ logits, int N)
{
    const int lane = threadIdx.x & 63;
    const int q    = lane >> 4;
    const int l16  = lane & 15;
    const int v    = blockIdx.x * 16 + (threadIdx.x >> 6) * 4 + q;
    if (v >= N) return;

    const int r0 = rowp[v], r1 = rowp[v + 1];
    const int head = l16 >> 2;
    const float erq = er[(size_t)v * 4 + head];

    float2 curA = *reinterpret_cast<const float2*>(&yel[(size_t)v * 8 + head * 2]);
    const float mref = leaky02(curA.y + erq);   // self-loop e (col[r0]==v)

    int jB = (r0 + 1 < r1) ? r0 + 1 : r1 - 1;
    int uB = col[jB];
    float2 curB = *reinterpret_cast<const float2*>(&yel[(size_t)uB * 8 + head * 2]);

    float S = 0.f, Acc = 0.f;
    for (int j = r0; j < r1; j += 2) {
        int jA2 = (j + 2 < r1) ? j + 2 : r1 - 1;
        int uA2 = col[jA2];
        float2 nA = *reinterpret_cast<const float2*>(&yel[(size_t)uA2 * 8 + head * 2]);

        {
            float e = leaky02(curA.y + erq);
            float d = fminf(e - mref, 80.f);
            float p = __expf(d);
            S += p; Acc += p * curA.x;
        }

        if (j + 1 < r1) {
            int jB2 = (j + 3 < r1) ? j + 3 : r1 - 1;
            int uB2 = col[jB2];
            float2 nB = *reinterpret_cast<const float2*>(&yel[(size_t)uB2 * 8 + head * 2]);

            float e = leaky02(curB.y + erq);
            float d = fminf(e - mref, 80.f);
            float p = __expf(d);
            S += p; Acc += p * curB.x;

            curB = nB;
        }
        curA = nA;
    }
    float part = Acc / S;
    part += __shfl_xor(part, 4, 64);
    part += __shfl_xor(part, 8, 64);
    if (l16 == 0) logits[v] = part + prm[16];
}

// ---------------------------------------------------------------------------
extern "C" void kernel_launch(void* const* d_in, const int* in_sizes, int n_in,
                              void* d_out, int out_size, void* d_ws, size_t ws_size,
                              hipStream_t stream)
{
    const float* weights = (const float*)d_in[0];
    const float* lin_W   = (const float*)d_in[1];
    const float* lin_b   = (const float*)d_in[2];
    const float* fc_W    = (const float*)d_in[3];
    const float* attn_l  = (const float*)d_in[4];
    const float* attn_r  = (const float*)d_in[5];
    const float* conv_b  = (const float*)d_in[6];
    const float* pred_W  = (const float*)d_in[7];
    const float* pred_b  = (const float*)d_in[8];
    const int*   src     = (const int*)d_in[9];
    const int*   dst     = (const int*)d_in[10];

    const int N = in_sizes[0];
    const int E = in_sizes[9];
    const int NB = (N + SCAN_TILE - 1) / SCAN_TILE;

    // workspace layout (16B-aligned sections)
    unsigned short* xb = (unsigned short*)d_ws;                    // N*128 bf16 (pre-activated)
    unsigned short* hb = xb + (size_t)N * 128;                     // N*128 bf16
    float* el  = (float*)(hb + (size_t)N * 128);                   // N*4
    float* er  = el + (size_t)N * 4;                               // N*4
    float* yel = er + (size_t)N * 4;                               // N*8 {y,el} per head
    float* c1  = yel + (size_t)N * 8;                              // 128
    float* c2  = c1 + 128;                                         // 128
    float* prm = c2 + 128;                                         // 32
    short* Whs = (short*)(prm + 32);                               // 2*16384 bf16 (packed)
    short* Wls = Whs + 2 * 16384;                                  // 2*16384 bf16 (packed)
    short* Mhs = Wls + 2 * 16384;                                  // 2*2048 bf16 (Mext hi)
    short* Mls = Mhs + 2 * 2048;                                   // 2*2048 bf16 (Mext lo)
    int*   deg  = (int*)(Mls + 2 * 2048);                          // N
    int*   rowp = deg + N;                                         // N+1
    int*   slot = rowp + (N + 1);                                  // E
    int*   col  = slot + E;                                        // E+N
    int*   bsum = col + (E + N);                                   // NB
    int*   bpre = bsum + NB;                                       // NB

    // CSR build + packed W split (fresh every call: ws is re-poisoned)
    init_split_kernel<<<(N + 255) / 256, 256, 0, stream>>>(
        deg, N, fc_W + 16384, Whs, Wls, 2 * 16384);
    mlr_prep_kernel<<<2, 1024, 0, stream>>>(fc_W, attn_l, attn_r, Mhs, Mls);
    deg_count_slot_kernel<<<(E + 255) / 256, 256, 0, stream>>>(dst, deg, slot, E);
    scanA_kernel<<<NB, 256, 0, stream>>>(deg, bsum, N);
    scanB_kernel<<<1, 1024, 0, stream>>>(bsum, bpre, rowp, NB, N);
    scanC_kernel<<<NB, 256, 0, stream>>>(deg, bpre, rowp, col, N);
    scatter2_kernel<<<(E + 255) / 256, 256, 0, stream>>>(src, dst, slot, rowp, col, E);

    rank1_prep_kernel<<<1, 1024, 0, stream>>>(
        lin_W, lin_b, fc_W, attn_l, attn_r, conv_b + 2 * 128, pred_W, pred_b,
        c1, c2, prm);

    // Layer 0: rank-1 aggregation straight from w (no h0 materialization)
    agg0_kernel<<<(N + 15) / 16, 256, 0, stream>>>(
        weights, c1, c2, prm, rowp, col, conv_b, xb, N);

    // Layer 1: gemm (mode 0) + full-gather aggregation
    gemm_mfma_kernel<<<(N + 127) / 128, 256, 0, stream>>>(
        xb, Whs, Wls, Mhs, Mls, hb, el, er, pred_W, yel, N, 0);
    agg_mid_kernel<<<(N + 15) / 16, 256, 0, stream>>>(
        hb, el, er, rowp, col, conv_b + 128, xb, N);

    // Layer 2: gemm (mode 1: y=h.pW + el packed) + light aggregation
    gemm_mfma_kernel<<<(N + 127) / 128, 256, 0, stream>>>(
        xb, Whs + 16384, Wls + 16384, Mhs + 2048, Mls + 2048,
        hb, el, er, pred_W, yel, N, 1);
    agg2_kernel<<<(N + 15) / 16, 256, 0, stream>>>(
        yel, er, rowp, col, prm, (float*)d_out, N);
}

// Round 6
// 251.758 us; speedup vs baseline: 1.4946x; 1.0906x over previous
//
#include <hip/hip_runtime.h>
#include <hip/hip_bf16.h>
#include <math.h>

// Problem constants: N=100000, E=600000, D=128, H=4, F=32, L=3

__device__ __forceinline__ float leaky02(float x) {
    return x >= 0.f ? x : 0.2f * x;
}
__device__ __forceinline__ float leaky01(float x) {
    return x >= 0.f ? x : 0.01f * x;
}

// bf16 helpers (round-to-nearest-even)
__device__ __forceinline__ unsigned short f2bf(float f) {
    unsigned u = __float_as_uint(f);
    unsigned r = u + 0x7FFFu + ((u >> 16) & 1u);
    return (unsigned short)(r >> 16);
}
__device__ __forceinline__ float bf2f(unsigned short s) {
    return __uint_as_float(((unsigned)s) << 16);
}

typedef __attribute__((ext_vector_type(8))) short bf16x8;
typedef __attribute__((ext_vector_type(8))) unsigned short u16x8;
typedef __attribute__((ext_vector_type(4))) float f32x4;

// ---------------------------------------------------------------------------
// FUSED PREP (one launch, block-range dispatch; the three jobs are
// mutually independent):
//   blocks [0, nbi)   : deg[i]=1 init + W split into bf16 hi/lo (packed)
//   blocks nbi, nbi+1 : Mext rows for layers 1,2 (one thread per element)
//   block  nbi+2      : layer-0 rank-1 constants + epilogue constant
__global__ __launch_bounds__(1024) void prep_kernel(
    int* __restrict__ deg, int N,
    const float* __restrict__ fc_W, const float* __restrict__ attn_l,
    const float* __restrict__ attn_r,
    short* __restrict__ Wh, short* __restrict__ Wl,
    short* __restrict__ Mh, short* __restrict__ Ml,
    const float* __restrict__ lW, const float* __restrict__ lb,
    const float* __restrict__ cb2, const float* __restrict__ pW,
    const float* __restrict__ pb,
    float* __restrict__ c1, float* __restrict__ c2, float* __restrict__ prm)
{
    const int nbi = (N + 1023) >> 10;
    const int b = blockIdx.x;
    const int t = threadIdx.x;

    if (b < nbi) {
        // --- init_split job ---
        int i = b * 1024 + t;
        if (i < N) deg[i] = 1;
        if (i < 2 * 16384) {
            const float* W = fc_W + 16384;   // layers 1,2
            int l    = i >> 14;
            int p    = i & 16383;
            int j    = p & 7;
            int lane = (p >> 3) & 63;
            int c    = (p >> 9) & 7;
            int kk   = p >> 12;
            int mr   = lane & 15;
            int quad = lane >> 4;
            int row  = c * 16 + mr;
            int d    = kk * 32 + quad * 8 + j;
            float f = W[(size_t)l * 16384 + row * 128 + d];
            unsigned short hi = f2bf(f);
            Wh[i] = (short)hi;
            Wl[i] = (short)f2bf(f - bf2f(hi));
        }
    } else if (b < nbi + 2) {
        // --- mlr_prep job (layer l+1) ---
        int l = b - nbi;
        const float* W  = fc_W + (size_t)(l + 1) * 16384;
        const float* al = attn_l + (l + 1) * 128;
        const float* ar = attn_r + (l + 1) * 128;
        short* mh = Mh + (size_t)l * 16 * 128;
        short* ml = Ml + (size_t)l * 16 * 128;
        int r = t >> 7;                       // 0..7
        int d = t & 127;
        int hh = r & 3;
        const float* av = (r < 4) ? al : ar;
        float s = 0.f;
#pragma unroll
        for (int f = 0; f < 32; ++f)
            s += W[(size_t)(hh * 32 + f) * 128 + d] * av[hh * 32 + f];
        unsigned short hi = f2bf(s);
        mh[r * 128 + d] = (short)hi;
        ml[r * 128 + d] = (short)f2bf(s - bf2f(hi));
        mh[(r + 8) * 128 + d] = 0;            // zero rows 8..15
        ml[(r + 8) * 128 + d] = 0;
    } else {
        // --- rank1_prep job ---
        __shared__ float sh1[128], sh2[128], sh3[128], sh4[128], sh5[128];
        const float* W0 = fc_W;
        const float* al = attn_l;
        const float* ar = attn_r;
        int j = t >> 3, sub = t & 7;          // 8 consecutive lanes per j
        float s1 = 0.f, s2 = 0.f;
        int d0 = sub * 16;
#pragma unroll
        for (int k = 0; k < 16; ++k) {
            float wv = W0[j * 128 + d0 + k];
            s1 += lW[d0 + k] * wv;
            s2 += lb[d0 + k] * wv;
        }
#pragma unroll
        for (int m = 1; m <= 4; m <<= 1) {
            s1 += __shfl_xor(s1, m, 64);
            s2 += __shfl_xor(s2, m, 64);
        }
        if (sub == 0) {
            c1[j] = s1; c2[j] = s2;
            sh1[j] = s1 * al[j]; sh2[j] = s2 * al[j];
            sh3[j] = s1 * ar[j]; sh4[j] = s2 * ar[j];
            sh5[j] = cb2[j] * pW[j];
        }
        __syncthreads();
        if (t < 4) {
            float p = 0.f, q = 0.f, r = 0.f, s = 0.f;
            for (int f = 0; f < 32; ++f) {
                p += sh1[t * 32 + f]; q += sh2[t * 32 + f];
                r += sh3[t * 32 + f]; s += sh4[t * 32 + f];
            }
            prm[t] = p; prm[4 + t] = q; prm[8 + t] = r; prm[12 + t] = s;
        }
        if (t == 0) {
            float cs = 0.f;
            for (int k = 0; k < 128; ++k) cs += sh5[k];
            prm[16] = cs + pb[0];
        }
    }
}

// slot[i] = old count (>=1 because self loop holds slot 0)
__global__ __launch_bounds__(256) void deg_count_slot_kernel(
    const int* __restrict__ dst, int* __restrict__ deg,
    int* __restrict__ slot, int E)
{
    int i = blockIdx.x * 256 + threadIdx.x;
    if (i < E) slot[i] = atomicAdd(&deg[dst[i]], 1);
}

#define SCAN_TILE 1024

__global__ __launch_bounds__(256) void scanA_kernel(
    const int* __restrict__ deg, int* __restrict__ bsum, int N)
{
    __shared__ int ws[4];
    int b = blockIdx.x, t = threadIdx.x;
    int base = b * SCAN_TILE + t * 4;
    int s = 0;
#pragma unroll
    for (int k = 0; k < 4; ++k) {
        int i = base + k;
        if (i < N) s += deg[i];
    }
#pragma unroll
    for (int m = 32; m >= 1; m >>= 1) s += __shfl_xor(s, m, 64);
    if ((t & 63) == 0) ws[t >> 6] = s;
    __syncthreads();
    if (t == 0) bsum[b] = ws[0] + ws[1] + ws[2] + ws[3];
}

__global__ __launch_bounds__(1024) void scanB_kernel(
    int* __restrict__ bsum, int* __restrict__ bpre, int* __restrict__ rowp,
    int NB, int N)
{
    __shared__ int sh[1024];
    int t = threadIdx.x;
    int v = (t < NB) ? bsum[t] : 0;
    sh[t] = v;
    __syncthreads();
    for (int off = 1; off < 1024; off <<= 1) {
        int u = (t >= off) ? sh[t - off] : 0;
        __syncthreads();
        sh[t] += u;
        __syncthreads();
    }
    if (t < NB) bpre[t] = sh[t] - v;          // exclusive prefix
    if (t == 1023) rowp[N] = sh[1023];        // total
}

// scanC also writes the self-loop entry: col[rowp[i]] = i (slot 0).
__global__ __launch_bounds__(256) void scanC_kernel(
    const int* __restrict__ deg, const int* __restrict__ bpre,
    int* __restrict__ rowp, int* __restrict__ col, int N)
{
    __shared__ int sh[256];
    int b = blockIdx.x, t = threadIdx.x;
    int base = b * SCAN_TILE + t * 4;
    int v[4];
#pragma unroll
    for (int k = 0; k < 4; ++k) {
        int i = base + k;
        v[k] = (i < N) ? deg[i] : 0;
    }
    int tsum = v[0] + v[1] + v[2] + v[3];
    sh[t] = tsum;
    __syncthreads();
    for (int off = 1; off < 256; off <<= 1) {
        int u = (t >= off) ? sh[t - off] : 0;
        __syncthreads();
        sh[t] += u;
        __syncthreads();
    }
    int pre = bpre[b] + sh[t] - tsum;
#pragma unroll
    for (int k = 0; k < 4; ++k) {
        int i = base + k;
        if (i < N) {
            rowp[i] = pre;
            col[pre] = i;   // self loop at slot 0
        }
        pre += v[k];
    }
}

// atomic-free scatter: position fully determined by rowp + recorded slot
__global__ __launch_bounds__(256) void scatter2_kernel(
    const int* __restrict__ src, const int* __restrict__ dst,
    const int* __restrict__ slot, const int* __restrict__ rowp,
    int* __restrict__ col, int E)
{
    int i = blockIdx.x * 256 + threadIdx.x;
    if (i < E) col[rowp[dst[i]] + slot[i]] = src[i];
}

// ---------------------------------------------------------------------------
// LAYER-0 aggregation via rank-1 identity — EDGE-PARALLEL across the 4
// lanes of each (vertex,head) group (lane e4 = l16&3 takes edges
// r0+e4, r0+e4+4, ...). Serial dependent-load chain drops deg -> deg/4;
// the merge is 2 scalars (S, Sw) x 2 shfl_xor — no online-max state.
__global__ __launch_bounds__(256) void agg0_kernel(
    const float* __restrict__ w, const float* __restrict__ c1,
    const float* __restrict__ c2, const float* __restrict__ prm,
    const int* __restrict__ rowp, const int* __restrict__ col,
    const float* __restrict__ bias, unsigned short* __restrict__ xout, int N)
{
    const int lane = threadIdx.x & 63;
    const int q    = lane >> 4;
    const int l16  = lane & 15;
    const int v    = blockIdx.x * 16 + (threadIdx.x >> 6) * 4 + q;
    if (v >= N) return;

    const int r0 = rowp[v], r1 = rowp[v + 1];
    const int head = l16 >> 2;
    const int e4   = l16 & 3;        // edge slot within head group
    const int f0   = l16 * 8;
    const float pl = prm[head],     ql = prm[4 + head];
    const float pr = prm[8 + head], qr = prm[12 + head];

    const float wv  = w[v];
    const float erq = wv * pr + qr;
    const float mref = leaky02(wv * pl + ql + erq);   // self-loop e

    float S = 0.f, Sw = 0.f;
    for (int j = r0 + e4; j < r1; j += 4) {
        int u = col[j];                                // (j==r0 -> u==v)
        float wu = w[u];
        float e = leaky02(wu * pl + ql + erq);
        float d = fminf(e - mref, 80.f);
        float p = __expf(d);
        S += p; Sw += p * wu;
    }
    // quad-reduce (lanes of a head group are 4 consecutive lanes)
    S  += __shfl_xor(S, 1, 64);  S  += __shfl_xor(S, 2, 64);
    Sw += __shfl_xor(Sw, 1, 64); Sw += __shfl_xor(Sw, 2, 64);
    const float t = Sw / S;

    float4 a0 = *reinterpret_cast<const float4*>(&c1[f0]);
    float4 a1 = *reinterpret_cast<const float4*>(&c1[f0 + 4]);
    float4 g0 = *reinterpret_cast<const float4*>(&c2[f0]);
    float4 g1 = *reinterpret_cast<const float4*>(&c2[f0 + 4]);
    float4 b0 = *reinterpret_cast<const float4*>(&bias[f0]);
    float4 b1 = *reinterpret_cast<const float4*>(&bias[f0 + 4]);
    const float aa[8] = {a0.x, a0.y, a0.z, a0.w, a1.x, a1.y, a1.z, a1.w};
    const float gg[8] = {g0.x, g0.y, g0.z, g0.w, g1.x, g1.y, g1.z, g1.w};
    const float bb[8] = {b0.x, b0.y, b0.z, b0.w, b1.x, b1.y, b1.z, b1.w};

    u16x8 o;
#pragma unroll
    for (int k = 0; k < 8; ++k)
        o[k] = f2bf(leaky01(t * aa[k] + gg[k] + bb[k]));
    *reinterpret_cast<u16x8*>(&xout[(size_t)v * 128 + f0]) = o;
}

// ---------------------------------------------------------------------------
// MFMA bf16 GEMM (layers 1,2) + fused el/er tile — 32 rows/wave,
// FRAGMENT-PACKED W. mode 0 (layer1): write hb + el + er.
// mode 1 (layer2): skip hb; write yel[row*8+h*2] = {y_h = h.pW_h, el_h} + er.
__global__ __launch_bounds__(256) void gemm_mfma_kernel(
    const unsigned short* __restrict__ xb, const short* __restrict__ Wh,
    const short* __restrict__ Wl, const short* __restrict__ Mh,
    const short* __restrict__ Ml, unsigned short* __restrict__ hb,
    float* __restrict__ el, float* __restrict__ er,
    const float* __restrict__ pW, float* __restrict__ yel,
    int N, int mode)
{
    const int lane = threadIdx.x & 63;
    const int wv   = threadIdx.x >> 6;
    const int m0   = blockIdx.x * 128 + wv * 32;  // 32 rows per wave
    const int mr   = lane & 15;
    const int quad = lane >> 4;

    int r0 = m0 + mr;      if (r0 > N - 1) r0 = N - 1;   // clamped load rows
    int r1 = m0 + 16 + mr; if (r1 > N - 1) r1 = N - 1;
    const unsigned short* xp0 = xb + (size_t)r0 * 128 + quad * 8;
    const unsigned short* xp1 = xb + (size_t)r1 * 128 + quad * 8;

    f32x4 acc0[8], acc1[8], acce0, acce1;
#pragma unroll
    for (int c = 0; c < 8; ++c) {
        acc0[c] = (f32x4){0.f, 0.f, 0.f, 0.f};
        acc1[c] = (f32x4){0.f, 0.f, 0.f, 0.f};
    }
    acce0 = (f32x4){0.f, 0.f, 0.f, 0.f};
    acce1 = (f32x4){0.f, 0.f, 0.f, 0.f};

#pragma unroll
    for (int kk = 0; kk < 4; ++kk) {
        bf16x8 a0 = *reinterpret_cast<const bf16x8*>(xp0 + kk * 32);
        bf16x8 a1 = *reinterpret_cast<const bf16x8*>(xp1 + kk * 32);

        const int kb = kk * 32 + quad * 8;
        bf16x8 bh[8], bl[8];
#pragma unroll
        for (int c = 0; c < 8; ++c) {
            const size_t wo = (size_t)((kk * 8 + c) * 64 + lane) * 8;
            bh[c] = *reinterpret_cast<const bf16x8*>(Wh + wo);
            bl[c] = *reinterpret_cast<const bf16x8*>(Wl + wo);
        }
        bf16x8 eh = *reinterpret_cast<const bf16x8*>(Mh + (size_t)mr * 128 + kb);
        bf16x8 eo = *reinterpret_cast<const bf16x8*>(Ml + (size_t)mr * 128 + kb);
#pragma unroll
        for (int c = 0; c < 8; ++c) {
            acc0[c] = __builtin_amdgcn_mfma_f32_16x16x32_bf16(a0, bh[c], acc0[c], 0, 0, 0);
            acc0[c] = __builtin_amdgcn_mfma_f32_16x16x32_bf16(a0, bl[c], acc0[c], 0, 0, 0);
            acc1[c] = __builtin_amdgcn_mfma_f32_16x16x32_bf16(a1, bh[c], acc1[c], 0, 0, 0);
            acc1[c] = __builtin_amdgcn_mfma_f32_16x16x32_bf16(a1, bl[c], acc1[c], 0, 0, 0);
        }
        acce0 = __builtin_amdgcn_mfma_f32_16x16x32_bf16(a0, eh, acce0, 0, 0, 0);
        acce0 = __builtin_amdgcn_mfma_f32_16x16x32_bf16(a0, eo, acce0, 0, 0, 0);
        acce1 = __builtin_amdgcn_mfma_f32_16x16x32_bf16(a1, eh, acce1, 0, 0, 0);
        acce1 = __builtin_amdgcn_mfma_f32_16x16x32_bf16(a1, eo, acce1, 0, 0, 0);
    }

    if (mode == 0) {
#pragma unroll
        for (int i = 0; i < 4; ++i) {
            int rowA = m0 + quad * 4 + i;
            if (rowA < N) {
                unsigned short* hp = hb + (size_t)rowA * 128 + mr;
#pragma unroll
                for (int c = 0; c < 8; ++c) hp[c * 16] = f2bf(acc0[c][i]);
                if (mr < 4)       el[(size_t)rowA * 4 + mr]       = acce0[i];
                else if (mr < 8)  er[(size_t)rowA * 4 + (mr - 4)] = acce0[i];
            }
            int rowB = m0 + 16 + quad * 4 + i;
            if (rowB < N) {
                unsigned short* hp = hb + (size_t)rowB * 128 + mr;
#pragma unroll
                for (int c = 0; c < 8; ++c) hp[c * 16] = f2bf(acc1[c][i]);
                if (mr < 4)       el[(size_t)rowB * 4 + mr]       = acce1[i];
                else if (mr < 8)  er[(size_t)rowB * 4 + (mr - 4)] = acce1[i];
            }
        }
    } else {
        // y_h = sum_f h[row, 32h..32h+31] * pW[...]; feature f = mr + c*16
        float pw[8];
#pragma unroll
        for (int c = 0; c < 8; ++c) pw[c] = pW[mr + c * 16];
#pragma unroll
        for (int i = 0; i < 4; ++i) {
            int rowA = m0 + quad * 4 + i;
            {
                float y[4];
#pragma unroll
                for (int h = 0; h < 4; ++h)
                    y[h] = acc0[2 * h][i] * pw[2 * h] + acc0[2 * h + 1][i] * pw[2 * h + 1];
#pragma unroll
                for (int d = 1; d < 16; d <<= 1) {
#pragma unroll
                    for (int h = 0; h < 4; ++h) y[h] += __shfl_xor(y[h], d, 64);
                }
                if (rowA < N) {
                    if (mr < 4) {
                        float2 o; o.x = y[mr]; o.y = acce0[i];
                        *reinterpret_cast<float2*>(&yel[(size_t)rowA * 8 + mr * 2]) = o;
                    } else if (mr < 8) {
                        er[(size_t)rowA * 4 + (mr - 4)] = acce0[i];
                    }
                }
            }
            int rowB = m0 + 16 + quad * 4 + i;
            {
                float y[4];
#pragma unroll
                for (int h = 0; h < 4; ++h)
                    y[h] = acc1[2 * h][i] * pw[2 * h] + acc1[2 * h + 1][i] * pw[2 * h + 1];
#pragma unroll
                for (int d = 1; d < 16; d <<= 1) {
#pragma unroll
                    for (int h = 0; h < 4; ++h) y[h] += __shfl_xor(y[h], d, 64);
                }
                if (rowB < N) {
                    if (mr < 4) {
                        float2 o; o.x = y[mr]; o.y = acce1[i];
                        *reinterpret_cast<float2*>(&yel[(size_t)rowB * 8 + mr * 2]) = o;
                    } else if (mr < 8) {
                        er[(size_t)rowB * 4 + (mr - 4)] = acce1[i];
                    }
                }
            }
        }
    }
}

// ---------------------------------------------------------------------------
// MIDDLE-layer aggregation — depth-2 two-stream pipeline (kept; the
// kernel sits at the random-gather fabric ceiling, ~2.4TB/s L2-miss).
__global__ __launch_bounds__(256) void agg_mid_kernel(
    const unsigned short* __restrict__ hb, const float* __restrict__ el,
    const float* __restrict__ er, const int* __restrict__ rowp,
    const int* __restrict__ col, const float* __restrict__ bias,
    unsigned short* __restrict__ xout, int N)
{
    const int lane = threadIdx.x & 63;
    const int q    = lane >> 4;
    const int l16  = lane & 15;
    const int v    = blockIdx.x * 16 + (threadIdx.x >> 6) * 4 + q;
    if (v >= N) return;

    const int r0 = rowp[v], r1 = rowp[v + 1];
    const int head = l16 >> 2;
    const int f0   = l16 * 8;
    const float erq = er[(size_t)v * 4 + head];
    const float el_self = el[(size_t)v * 4 + head];
    const float mref = leaky02(el_self + erq);

    float s = 0.f;
    float acc[8];
#pragma unroll
    for (int k = 0; k < 8; ++k) acc[k] = 0.f;

    // prologue: A holds edge r0 (self loop, col[r0]==v), B holds edge r0+1
    float elA = el_self;
    u16x8 hvA = *reinterpret_cast<const u16x8*>(&hb[(size_t)v * 128 + f0]);
    int jB = (r0 + 1 < r1) ? r0 + 1 : r1 - 1;
    int uB = col[jB];
    float elB = el[(size_t)uB * 4 + head];
    u16x8 hvB = *reinterpret_cast<const u16x8*>(&hb[(size_t)uB * 128 + f0]);

    for (int j = r0; j < r1; j += 2) {
        // prefetch A-stream edge j+2 (clamped to a valid edge)
        int jA2 = (j + 2 < r1) ? j + 2 : r1 - 1;
        int uA2 = col[jA2];
        float elA2 = el[(size_t)uA2 * 4 + head];
        u16x8 hvA2 = *reinterpret_cast<const u16x8*>(&hb[(size_t)uA2 * 128 + f0]);

        // compute edge j from A state (its load was issued 2 edges ago)
        {
            float e = leaky02(elA + erq);
            float d = fminf(e - mref, 80.f);
            float p = __expf(d);
            s += p;
#pragma unroll
            for (int k = 0; k < 8; ++k) acc[k] += p * bf2f(hvA[k]);
        }

        if (j + 1 < r1) {
            // prefetch B-stream edge j+3
            int jB2 = (j + 3 < r1) ? j + 3 : r1 - 1;
            int uB2 = col[jB2];
            float elB2 = el[(size_t)uB2 * 4 + head];
            u16x8 hvB2 = *reinterpret_cast<const u16x8*>(&hb[(size_t)uB2 * 128 + f0]);

            // compute edge j+1 from B state
            float e = leaky02(elB + erq);
            float d = fminf(e - mref, 80.f);
            float p = __expf(d);
            s += p;
#pragma unroll
            for (int k = 0; k < 8; ++k) acc[k] += p * bf2f(hvB[k]);

            elB = elB2; hvB = hvB2;
        }
        elA = elA2; hvA = hvA2;
    }
    const float is = 1.f / s;

    float4 b0 = *reinterpret_cast<const float4*>(&bias[f0]);
    float4 b1 = *reinterpret_cast<const float4*>(&bias[f0 + 4]);
    const float bb[8] = {b0.x, b0.y, b0.z, b0.w, b1.x, b1.y, b1.z, b1.w};

    u16x8 o;
#pragma unroll
    for (int k = 0; k < 8; ++k) o[k] = f2bf(leaky01(acc[k] * is + bb[k]));
    *reinterpret_cast<u16x8*>(&xout[(size_t)v * 128 + f0]) = o;
}

// ---------------------------------------------------------------------------
// LAST-layer aggregation — EDGE-PARALLEL across the 4 lanes of each
// (vertex,head) group; merge is 2 scalars (S, A) x 2 shfl_xor.
__global__ __launch_bounds__(256) void agg2_kernel(
    const float* __restrict__ yel, const float* __restrict__ er,
    const int* __restrict__ rowp, const int* __restrict__ col,
    const float* __restrict__ prm, float* __restrict__ logits, int N)
{
    const int lane = threadIdx.x & 63;
    const int q    = lane >> 4;
    const int l16  = lane & 15;
    const int v    = blockIdx.x * 16 + (threadIdx.x >> 6) * 4 + q;
    if (v >= N) return;

    const int r0 = rowp[v], r1 = rowp[v + 1];
    const int head = l16 >> 2;
    const int e4   = l16 & 3;
    const float erq = er[(size_t)v * 4 + head];

    float2 selfy = *reinterpret_cast<const float2*>(&yel[(size_t)v * 8 + head * 2]);
    const float mref = leaky02(selfy.y + erq);   // self-loop e (col[r0]==v)

    float S = 0.f, A = 0.f;
    for (int j = r0 + e4; j < r1; j += 4) {
        int u = col[j];
        float2 c = *reinterpret_cast<const float2*>(&yel[(size_t)u * 8 + head * 2]);
        float e = leaky02(c.y + erq);
        float d = fminf(e - mref, 80.f);
        float p = __expf(d);
        S += p; A += p * c.x;
    }
    // quad-reduce within head group, then sum the 4 heads
    S += __shfl_xor(S, 1, 64); S += __shfl_xor(S, 2, 64);
    A += __shfl_xor(A, 1, 64); A += __shfl_xor(A, 2, 64);
    float part = A / S;
    part += __shfl_xor(part, 4, 64);
    part += __shfl_xor(part, 8, 64);
    if (l16 == 0) logits[v] = part + prm[16];
}

// ---------------------------------------------------------------------------
extern "C" void kernel_launch(void* const* d_in, const int* in_sizes, int n_in,
                              void* d_out, int out_size, void* d_ws, size_t ws_size,
                              hipStream_t stream)
{
    const float* weights = (const float*)d_in[0];
    const float* lin_W   = (const float*)d_in[1];
    const float* lin_b   = (const float*)d_in[2];
    const float* fc_W    = (const float*)d_in[3];
    const float* attn_l  = (const float*)d_in[4];
    const float* attn_r  = (const float*)d_in[5];
    const float* conv_b  = (const float*)d_in[6];
    const float* pred_W  = (const float*)d_in[7];
    const float* pred_b  = (const float*)d_in[8];
    const int*   src     = (const int*)d_in[9];
    const int*   dst     = (const int*)d_in[10];

    const int N = in_sizes[0];
    const int E = in_sizes[9];
    const int NB = (N + SCAN_TILE - 1) / SCAN_TILE;
    const int NBI = (N + 1023) / 1024;

    // workspace layout (16B-aligned sections)
    unsigned short* xb = (unsigned short*)d_ws;                    // N*128 bf16 (pre-activated)
    unsigned short* hb = xb + (size_t)N * 128;                     // N*128 bf16
    float* el  = (float*)(hb + (size_t)N * 128);                   // N*4
    float* er  = el + (size_t)N * 4;                               // N*4
    float* yel = er + (size_t)N * 4;                               // N*8 {y,el} per head
    float* c1  = yel + (size_t)N * 8;                              // 128
    float* c2  = c1 + 128;                                         // 128
    float* prm = c2 + 128;                                         // 32
    short* Whs = (short*)(prm + 32);                               // 2*16384 bf16 (packed)
    short* Wls = Whs + 2 * 16384;                                  // 2*16384 bf16 (packed)
    short* Mhs = Wls + 2 * 16384;                                  // 2*2048 bf16 (Mext hi)
    short* Mls = Mhs + 2 * 2048;                                   // 2*2048 bf16 (Mext lo)
    int*   deg  = (int*)(Mls + 2 * 2048);                          // N
    int*   rowp = deg + N;                                         // N+1
    int*   slot = rowp + (N + 1);                                  // E
    int*   col  = slot + E;                                        // E+N
    int*   bsum = col + (E + N);                                   // NB
    int*   bpre = bsum + NB;                                       // NB

    // Fused prep: deg init + W split + Mext + rank-1 constants (1 launch)
    prep_kernel<<<NBI + 3, 1024, 0, stream>>>(
        deg, N, fc_W, attn_l, attn_r, Whs, Wls, Mhs, Mls,
        lin_W, lin_b, conv_b + 2 * 128, pred_W, pred_b, c1, c2, prm);

    // CSR build
    deg_count_slot_kernel<<<(E + 255) / 256, 256, 0, stream>>>(dst, deg, slot, E);
    scanA_kernel<<<NB, 256, 0, stream>>>(deg, bsum, N);
    scanB_kernel<<<1, 1024, 0, stream>>>(bsum, bpre, rowp, NB, N);
    scanC_kernel<<<NB, 256, 0, stream>>>(deg, bpre, rowp, col, N);
    scatter2_kernel<<<(E + 255) / 256, 256, 0, stream>>>(src, dst, slot, rowp, col, E);

    // Layer 0: rank-1 aggregation straight from w (no h0 materialization)
    agg0_kernel<<<(N + 15) / 16, 256, 0, stream>>>(
        weights, c1, c2, prm, rowp, col, conv_b, xb, N);

    // Layer 1: gemm (mode 0) + full-gather aggregation
    gemm_mfma_kernel<<<(N + 127) / 128, 256, 0, stream>>>(
        xb, Whs, Wls, Mhs, Mls, hb, el, er, pred_W, yel, N, 0);
    agg_mid_kernel<<<(N + 15) / 16, 256, 0, stream>>>(
        hb, el, er, rowp, col, conv_b + 128, xb, N);

    // Layer 2: gemm (mode 1: y=h.pW + el packed) + light aggregation
    gemm_mfma_kernel<<<(N + 127) / 128, 256, 0, stream>>>(
        xb, Whs + 16384, Wls + 16384, Mhs + 2048, Mls + 2048,
        hb, el, er, pred_W, yel, N, 1);
    agg2_kernel<<<(N + 15) / 16, 256, 0, stream>>>(
        yel, er, rowp, col, prm, (float*)d_out, N);
}